// Round 1
// baseline (2845.040 us; speedup 1.0000x reference)
//
#include <hip/hip_runtime.h>

#define NSTEPS 10

__device__ __forceinline__ float sigmoidf_(float x) { return 1.0f / (1.0f + __expf(-x)); }

// ---------------------------------------------------------------------------
// k_dense: C[rows,128] = act(X[rows,K] @ W[K,128] (+ bias))
// block 256 threads, tile = 64 rows x 128 cols, per-thread 4x8 register tile
// ---------------------------------------------------------------------------
template<int K, bool RELU, bool BIAS>
__global__ __launch_bounds__(256) void k_dense(
    const float* __restrict__ X, const float* __restrict__ W,
    const float* __restrict__ bias, float* __restrict__ C, int rows)
{
  constexpr int KP = K + 1;               // odd stride -> 2-way LDS aliasing (free)
  __shared__ float Xs[64 * KP];
  __shared__ float Ws[32 * 128];
  const int t = threadIdx.x;
  const int rbase = blockIdx.x * 64;

  // stage X tile (row-major, coalesced 64B segments per 4-lane group)
  {
    const int r = t >> 2, q = t & 3;
    const int rg = rbase + r;
    #pragma unroll
    for (int i = 0; i < K / 16; ++i) {
      const int c = q * 4 + i * 16;
      float4 v = make_float4(0.f, 0.f, 0.f, 0.f);
      if (rg < rows) v = *(const float4*)(X + (size_t)rg * K + c);
      Xs[r * KP + c + 0] = v.x;
      Xs[r * KP + c + 1] = v.y;
      Xs[r * KP + c + 2] = v.z;
      Xs[r * KP + c + 3] = v.w;
    }
  }

  const int r0 = (t & 15) * 4;
  const int c0 = (t >> 4) * 8;
  float acc[4][8];
  #pragma unroll
  for (int j = 0; j < 4; ++j)
    #pragma unroll
    for (int c = 0; c < 8; ++c) acc[j][c] = 0.f;

  for (int p = 0; p < K / 32; ++p) {
    __syncthreads();
    #pragma unroll
    for (int i = 0; i < 4; ++i) {
      const int lin = t * 4 + i * 1024;
      *(float4*)(Ws + lin) = *(const float4*)(W + (size_t)p * 32 * 128 + lin);
    }
    __syncthreads();
    #pragma unroll 8
    for (int kk = 0; kk < 32; ++kk) {
      const int k = p * 32 + kk;
      const float x0 = Xs[(r0 + 0) * KP + k];
      const float x1 = Xs[(r0 + 1) * KP + k];
      const float x2 = Xs[(r0 + 2) * KP + k];
      const float x3 = Xs[(r0 + 3) * KP + k];
      const float4 w0 = *(const float4*)(Ws + kk * 128 + c0);
      const float4 w1 = *(const float4*)(Ws + kk * 128 + c0 + 4);
      const float wv[8] = {w0.x, w0.y, w0.z, w0.w, w1.x, w1.y, w1.z, w1.w};
      #pragma unroll
      for (int c = 0; c < 8; ++c) {
        acc[0][c] = fmaf(x0, wv[c], acc[0][c]);
        acc[1][c] = fmaf(x1, wv[c], acc[1][c]);
        acc[2][c] = fmaf(x2, wv[c], acc[2][c]);
        acc[3][c] = fmaf(x3, wv[c], acc[3][c]);
      }
    }
  }

  float bv[8];
  #pragma unroll
  for (int c = 0; c < 8; ++c) bv[c] = BIAS ? bias[c0 + c] : 0.f;
  #pragma unroll
  for (int j = 0; j < 4; ++j) {
    const int rg = rbase + r0 + j;
    if (rg >= rows) continue;
    float o[8];
    #pragma unroll
    for (int c = 0; c < 8; ++c) {
      float v = acc[j][c] + bv[c];
      if (RELU) v = fmaxf(v, 0.f);
      o[c] = v;
    }
    *(float4*)(C + (size_t)rg * 128 + c0)     = make_float4(o[0], o[1], o[2], o[3]);
    *(float4*)(C + (size_t)rg * 128 + c0 + 4) = make_float4(o[4], o[5], o[6], o[7]);
  }
}

// ---------------------------------------------------------------------------
// k_edge: per-edge fused MLP layers 2+3 + q-transform + segment output.
// h1 = relu(Pa[src] + Pb[dst] + b1)           (layer-1 partials precomputed)
// h2 = relu(h1 @ w2 + b2) ; m = h2 @ w3 + b3 ; mq = (feat@Qw+Qb).reshape(16,16) @ m
// PAIRED: factor f gets edges 2f,2f+1 -> pair-reduce in LDS, direct store.
// else:   atomicAdd into outMsg[dst].
// ---------------------------------------------------------------------------
template<bool PAIRED>
__global__ __launch_bounds__(256) void k_edge(
    const float* __restrict__ Pa, const float* __restrict__ Pb,
    const int* __restrict__ src, const int* __restrict__ dst,
    const float* __restrict__ feat,
    const float* __restrict__ b1,
    const float* __restrict__ w2, const float* __restrict__ b2,
    const float* __restrict__ w3, const float* __restrict__ b3,
    const float* __restrict__ Qw, const float* __restrict__ Qb,
    float* __restrict__ outMsg, int E)
{
  __shared__ float Xs[64 * 129];
  __shared__ float Ws[4096];
  __shared__ float MsT[16 * 66];
  __shared__ float Qs[1024];
  __shared__ float Qbs[256];
  __shared__ float feats[64 * 5];
  __shared__ float mqs[64 * 17];
  __shared__ int sidx[64];
  __shared__ int didx[64];

  const int t = threadIdx.x;
  const int e0 = blockIdx.x * 64;

  if (t < 64) {
    const int eg = e0 + t;
    sidx[t] = (eg < E) ? src[eg] : 0;
    didx[t] = (eg < E) ? dst[eg] : 0;
  }
  {
    const int e = t >> 2, k = t & 3;
    const int eg = e0 + e;
    feats[e * 5 + k] = (eg < E) ? feat[(size_t)eg * 4 + k] : 0.f;
  }
  *(float4*)(Qs + t * 4) = *(const float4*)(Qw + t * 4);
  if (t < 64) *(float4*)(Qbs + t * 4) = *(const float4*)(Qb + t * 4);
  __syncthreads();

  // ---- stage h1 tile ----
  {
    const int r = t >> 2, q = t & 3;
    const bool ok = (e0 + r) < E;
    const float* pa = Pa + (size_t)sidx[r] * 128;
    const float* pb = Pb + (size_t)didx[r] * 128;
    #pragma unroll
    for (int i = 0; i < 8; ++i) {
      const int c = q * 4 + i * 16;
      float4 v = make_float4(0.f, 0.f, 0.f, 0.f);
      if (ok) {
        const float4 a  = *(const float4*)(pa + c);
        const float4 b  = *(const float4*)(pb + c);
        const float4 bb = *(const float4*)(b1 + c);
        v.x = fmaxf(a.x + b.x + bb.x, 0.f);
        v.y = fmaxf(a.y + b.y + bb.y, 0.f);
        v.z = fmaxf(a.z + b.z + bb.z, 0.f);
        v.w = fmaxf(a.w + b.w + bb.w, 0.f);
      }
      Xs[r * 129 + c + 0] = v.x;
      Xs[r * 129 + c + 1] = v.y;
      Xs[r * 129 + c + 2] = v.z;
      Xs[r * 129 + c + 3] = v.w;
    }
  }

  // ---- h2 = relu(h1 @ w2 + b2), 4 k-panels of 32 ----
  const int r0 = (t & 15) * 4;
  const int c0 = (t >> 4) * 8;
  float acc[4][8];
  #pragma unroll
  for (int j = 0; j < 4; ++j)
    #pragma unroll
    for (int c = 0; c < 8; ++c) acc[j][c] = 0.f;

  for (int p = 0; p < 4; ++p) {
    __syncthreads();
    #pragma unroll
    for (int i = 0; i < 4; ++i) {
      const int lin = t * 4 + i * 1024;
      *(float4*)(Ws + lin) = *(const float4*)(w2 + (size_t)p * 4096 + lin);
    }
    __syncthreads();
    #pragma unroll 8
    for (int kk = 0; kk < 32; ++kk) {
      const int k = p * 32 + kk;
      const float x0 = Xs[(r0 + 0) * 129 + k];
      const float x1 = Xs[(r0 + 1) * 129 + k];
      const float x2 = Xs[(r0 + 2) * 129 + k];
      const float x3 = Xs[(r0 + 3) * 129 + k];
      const float4 w0 = *(const float4*)(Ws + kk * 128 + c0);
      const float4 w1 = *(const float4*)(Ws + kk * 128 + c0 + 4);
      const float wv[8] = {w0.x, w0.y, w0.z, w0.w, w1.x, w1.y, w1.z, w1.w};
      #pragma unroll
      for (int c = 0; c < 8; ++c) {
        acc[0][c] = fmaf(x0, wv[c], acc[0][c]);
        acc[1][c] = fmaf(x1, wv[c], acc[1][c]);
        acc[2][c] = fmaf(x2, wv[c], acc[2][c]);
        acc[3][c] = fmaf(x3, wv[c], acc[3][c]);
      }
    }
  }

  __syncthreads();
  // write h2 back into Xs (same layout), apply bias+relu
  {
    float bv[8];
    #pragma unroll
    for (int c = 0; c < 8; ++c) bv[c] = b2[c0 + c];
    #pragma unroll
    for (int j = 0; j < 4; ++j)
      #pragma unroll
      for (int c = 0; c < 8; ++c)
        Xs[(r0 + j) * 129 + c0 + c] = fmaxf(acc[j][c] + bv[c], 0.f);
  }
  // stage w3 [128,16] into Ws
  #pragma unroll
  for (int i = 0; i < 2; ++i) {
    const int lin = t * 4 + i * 1024;
    *(float4*)(Ws + lin) = *(const float4*)(w3 + lin);
  }
  __syncthreads();

  // ---- m = h2 @ w3 + b3 -> MsT[j][e] (transposed, stride 66) ----
  {
    const int em  = t >> 2;
    const int jm0 = (t & 3) * 4;
    float4 macc = make_float4(0.f, 0.f, 0.f, 0.f);
    #pragma unroll 8
    for (int k = 0; k < 128; ++k) {
      const float  x = Xs[em * 129 + k];
      const float4 w = *(const float4*)(Ws + k * 16 + jm0);
      macc.x = fmaf(x, w.x, macc.x);
      macc.y = fmaf(x, w.y, macc.y);
      macc.z = fmaf(x, w.z, macc.z);
      macc.w = fmaf(x, w.w, macc.w);
    }
    const float4 b = *(const float4*)(b3 + jm0);
    MsT[(jm0 + 0) * 66 + em] = macc.x + b.x;
    MsT[(jm0 + 1) * 66 + em] = macc.y + b.y;
    MsT[(jm0 + 2) * 66 + em] = macc.z + b.z;
    MsT[(jm0 + 3) * 66 + em] = macc.w + b.w;
  }
  __syncthreads();

  // ---- q-transform: mq[i] = sum_k feat_k * (Qw[k,i,:] . m) + Qb[i,:] . m ----
  {
    const int e  = t & 63;
    const int ig = (t >> 6) * 4;
    float mreg[16];
    #pragma unroll
    for (int j = 0; j < 16; ++j) mreg[j] = MsT[j * 66 + e];
    float fv[4];
    #pragma unroll
    for (int k = 0; k < 4; ++k) fv[k] = feats[e * 5 + k];
    float mq[4];
    #pragma unroll
    for (int ii = 0; ii < 4; ++ii) {
      const int i = ig + ii;
      float a = 0.f;
      #pragma unroll
      for (int k = 0; k < 4; ++k) {
        float s = 0.f;
        #pragma unroll
        for (int j = 0; j < 16; ++j) s = fmaf(Qs[k * 256 + i * 16 + j], mreg[j], s);
        a = fmaf(fv[k], s, a);
      }
      float sb = 0.f;
      #pragma unroll
      for (int j = 0; j < 16; ++j) sb = fmaf(Qbs[i * 16 + j], mreg[j], sb);
      mq[ii] = a + sb;
    }
    if (PAIRED) {
      #pragma unroll
      for (int ii = 0; ii < 4; ++ii) mqs[e * 17 + ig + ii] = mq[ii];
    } else {
      if (e0 + e < E) {
        const int d = didx[e];
        #pragma unroll
        for (int ii = 0; ii < 4; ++ii)
          atomicAdd(outMsg + (size_t)d * 16 + ig + ii, mq[ii]);
      }
    }
  }

  if (PAIRED) {
    __syncthreads();
    const int f0 = e0 >> 1;
    #pragma unroll
    for (int u = 0; u < 2; ++u) {
      const int o  = t * 2 + u;
      const int fl = o >> 4, i = o & 15;
      const float v = mqs[(2 * fl) * 17 + i] + mqs[(2 * fl + 1) * 17 + i];
      if (e0 + 2 * fl < E)
        outMsg[(size_t)(f0 + fl) * 16 + i] = v;
    }
  }
}

// ---------------------------------------------------------------------------
// k_gru: h[r] = GRU(msg[r], h[r]) for 64-row tiles, gates as K=16/K=64 GEMMs.
// torch gate order r,z,n ; n = tanh(i_n + r * h_n) (i/h kept separate).
// ---------------------------------------------------------------------------
__global__ __launch_bounds__(256) void k_gru(
    const float* __restrict__ msg, float* __restrict__ h,
    const float* __restrict__ wih, const float* __restrict__ whh,
    const float* __restrict__ bih, const float* __restrict__ bhh, int rows)
{
  __shared__ float Wi[16 * 192];
  __shared__ float Wh[64 * 192];
  __shared__ float Hs[64 * 65];
  __shared__ float Ms[64 * 17];
  const int t = threadIdx.x;
  const int rbase = blockIdx.x * 64;

  #pragma unroll
  for (int i = 0; i < 3; ++i) {
    const int lin = t * 4 + i * 1024;
    *(float4*)(Wi + lin) = *(const float4*)(wih + lin);
  }
  #pragma unroll
  for (int i = 0; i < 12; ++i) {
    const int lin = t * 4 + i * 1024;
    *(float4*)(Wh + lin) = *(const float4*)(whh + lin);
  }
  {
    const int r = t >> 2, q = t & 3;
    const int rg = rbase + r;
    #pragma unroll
    for (int i = 0; i < 4; ++i) {
      const int c = q * 4 + i * 16;
      float4 v = make_float4(0.f, 0.f, 0.f, 0.f);
      if (rg < rows) v = *(const float4*)(h + (size_t)rg * 64 + c);
      Hs[r * 65 + c + 0] = v.x;
      Hs[r * 65 + c + 1] = v.y;
      Hs[r * 65 + c + 2] = v.z;
      Hs[r * 65 + c + 3] = v.w;
    }
    const int c = q * 4;
    float4 v = make_float4(0.f, 0.f, 0.f, 0.f);
    if (rg < rows) v = *(const float4*)(msg + (size_t)rg * 16 + c);
    Ms[r * 17 + c + 0] = v.x;
    Ms[r * 17 + c + 1] = v.y;
    Ms[r * 17 + c + 2] = v.z;
    Ms[r * 17 + c + 3] = v.w;
  }
  __syncthreads();

  const int r0 = (t >> 4) * 4;
  const int s0 = (t & 15) * 4;
  float ar[4][4], az[4][4], ani[4][4], anh[4][4];
  #pragma unroll
  for (int j = 0; j < 4; ++j)
    #pragma unroll
    for (int ss = 0; ss < 4; ++ss) { ar[j][ss] = 0.f; az[j][ss] = 0.f; ani[j][ss] = 0.f; anh[j][ss] = 0.f; }

  #pragma unroll 4
  for (int k = 0; k < 16; ++k) {
    const float4 wr = *(const float4*)(Wi + k * 192 + s0);
    const float4 wz = *(const float4*)(Wi + k * 192 + 64 + s0);
    const float4 wn = *(const float4*)(Wi + k * 192 + 128 + s0);
    #pragma unroll
    for (int j = 0; j < 4; ++j) {
      const float x = Ms[(r0 + j) * 17 + k];
      ar[j][0] = fmaf(x, wr.x, ar[j][0]); ar[j][1] = fmaf(x, wr.y, ar[j][1]);
      ar[j][2] = fmaf(x, wr.z, ar[j][2]); ar[j][3] = fmaf(x, wr.w, ar[j][3]);
      az[j][0] = fmaf(x, wz.x, az[j][0]); az[j][1] = fmaf(x, wz.y, az[j][1]);
      az[j][2] = fmaf(x, wz.z, az[j][2]); az[j][3] = fmaf(x, wz.w, az[j][3]);
      ani[j][0] = fmaf(x, wn.x, ani[j][0]); ani[j][1] = fmaf(x, wn.y, ani[j][1]);
      ani[j][2] = fmaf(x, wn.z, ani[j][2]); ani[j][3] = fmaf(x, wn.w, ani[j][3]);
    }
  }
  #pragma unroll 4
  for (int k = 0; k < 64; ++k) {
    const float4 wr = *(const float4*)(Wh + k * 192 + s0);
    const float4 wz = *(const float4*)(Wh + k * 192 + 64 + s0);
    const float4 wn = *(const float4*)(Wh + k * 192 + 128 + s0);
    #pragma unroll
    for (int j = 0; j < 4; ++j) {
      const float x = Hs[(r0 + j) * 65 + k];
      ar[j][0] = fmaf(x, wr.x, ar[j][0]); ar[j][1] = fmaf(x, wr.y, ar[j][1]);
      ar[j][2] = fmaf(x, wr.z, ar[j][2]); ar[j][3] = fmaf(x, wr.w, ar[j][3]);
      az[j][0] = fmaf(x, wz.x, az[j][0]); az[j][1] = fmaf(x, wz.y, az[j][1]);
      az[j][2] = fmaf(x, wz.z, az[j][2]); az[j][3] = fmaf(x, wz.w, az[j][3]);
      anh[j][0] = fmaf(x, wn.x, anh[j][0]); anh[j][1] = fmaf(x, wn.y, anh[j][1]);
      anh[j][2] = fmaf(x, wn.z, anh[j][2]); anh[j][3] = fmaf(x, wn.w, anh[j][3]);
    }
  }

  const float4 bir = *(const float4*)(bih + s0);
  const float4 bhr = *(const float4*)(bhh + s0);
  const float4 biz = *(const float4*)(bih + 64 + s0);
  const float4 bhz = *(const float4*)(bhh + 64 + s0);
  const float4 bin = *(const float4*)(bih + 128 + s0);
  const float4 bhn = *(const float4*)(bhh + 128 + s0);
  const float br[4] = {bir.x + bhr.x, bir.y + bhr.y, bir.z + bhr.z, bir.w + bhr.w};
  const float bz[4] = {biz.x + bhz.x, biz.y + bhz.y, biz.z + bhz.z, biz.w + bhz.w};
  const float bi[4] = {bin.x, bin.y, bin.z, bin.w};
  const float bh[4] = {bhn.x, bhn.y, bhn.z, bhn.w};

  #pragma unroll
  for (int j = 0; j < 4; ++j) {
    const int rg = rbase + r0 + j;
    if (rg >= rows) continue;
    float o[4];
    #pragma unroll
    for (int ss = 0; ss < 4; ++ss) {
      const float rr = sigmoidf_(ar[j][ss] + br[ss]);
      const float zz = sigmoidf_(az[j][ss] + bz[ss]);
      const float nn = tanhf(ani[j][ss] + bi[ss] + rr * (anh[j][ss] + bh[ss]));
      const float ho = Hs[(r0 + j) * 65 + s0 + ss];
      o[ss] = (1.f - zz) * nn + zz * ho;
    }
    *(float4*)(h + (size_t)rg * 64 + s0) = make_float4(o[0], o[1], o[2], o[3]);
  }
}

// ---------------------------------------------------------------------------
// k_readout: logits = T2 @ ro_w3 + b3 ; out = softmax (2 classes)
// ---------------------------------------------------------------------------
__global__ __launch_bounds__(256) void k_readout(
    const float* __restrict__ T2, const float* __restrict__ w3,
    const float* __restrict__ b3, float* __restrict__ out, int rows)
{
  const int n = blockIdx.x * 256 + threadIdx.x;
  if (n >= rows) return;
  float l0 = b3[0], l1 = b3[1];
  #pragma unroll 8
  for (int k = 0; k < 128; k += 4) {
    const float4 x = *(const float4*)(T2 + (size_t)n * 128 + k);
    l0 = fmaf(x.x, w3[(k + 0) * 2 + 0], l0);
    l0 = fmaf(x.y, w3[(k + 1) * 2 + 0], l0);
    l0 = fmaf(x.z, w3[(k + 2) * 2 + 0], l0);
    l0 = fmaf(x.w, w3[(k + 3) * 2 + 0], l0);
    l1 = fmaf(x.x, w3[(k + 0) * 2 + 1], l1);
    l1 = fmaf(x.y, w3[(k + 1) * 2 + 1], l1);
    l1 = fmaf(x.z, w3[(k + 2) * 2 + 1], l1);
    l1 = fmaf(x.w, w3[(k + 3) * 2 + 1], l1);
  }
  const float m = fmaxf(l0, l1);
  const float e0 = __expf(l0 - m), e1 = __expf(l1 - m);
  const float inv = 1.f / (e0 + e1);
  out[(size_t)n * 2 + 0] = e0 * inv;
  out[(size_t)n * 2 + 1] = e1 * inv;
}

// ---------------------------------------------------------------------------
extern "C" void kernel_launch(void* const* d_in, const int* in_sizes, int n_in,
                              void* d_out, int out_size, void* d_ws, size_t ws_size,
                              hipStream_t stream)
{
  const int*   v2f_src  = (const int*)d_in[0];
  const int*   v2f_dst  = (const int*)d_in[1];
  const int*   f2v_src  = (const int*)d_in[2];
  const int*   f2v_dst  = (const int*)d_in[3];
  const float* feat_v2f = (const float*)d_in[4];
  const float* feat_f2v = (const float*)d_in[5];
  const float* Qw    = (const float*)d_in[8];
  const float* Qb    = (const float*)d_in[9];
  const float* m1w1  = (const float*)d_in[10];
  const float* m1b1  = (const float*)d_in[11];
  const float* m1w2  = (const float*)d_in[12];
  const float* m1b2  = (const float*)d_in[13];
  const float* m1w3  = (const float*)d_in[14];
  const float* m1b3  = (const float*)d_in[15];
  const float* m2w1  = (const float*)d_in[16];
  const float* m2b1  = (const float*)d_in[17];
  const float* m2w2  = (const float*)d_in[18];
  const float* m2b2  = (const float*)d_in[19];
  const float* m2w3  = (const float*)d_in[20];
  const float* m2b3  = (const float*)d_in[21];
  const float* g1wih = (const float*)d_in[22];
  const float* g1whh = (const float*)d_in[23];
  const float* g1bih = (const float*)d_in[24];
  const float* g1bhh = (const float*)d_in[25];
  const float* g2wih = (const float*)d_in[26];
  const float* g2whh = (const float*)d_in[27];
  const float* g2bih = (const float*)d_in[28];
  const float* g2bhh = (const float*)d_in[29];
  const float* row1  = (const float*)d_in[30];
  const float* rob1  = (const float*)d_in[31];
  const float* row2  = (const float*)d_in[32];
  const float* rob2  = (const float*)d_in[33];
  const float* row3  = (const float*)d_in[34];
  const float* rob3  = (const float*)d_in[35];

  const int E = in_sizes[0];
  const int N = out_size / 2;   // n_nodes
  const int F = E / 2;          // 2 edges per factor by construction

  // workspace layout (fp32), ~57 MB total
  float* ws    = (float*)d_ws;
  float* var_h = ws;                               // N*64
  float* fac_h = var_h + (size_t)N * 64;           // F*64
  float* A     = fac_h + (size_t)F * 64;           // F*128 (src-side partials / T1)
  float* B     = A     + (size_t)F * 128;          // F*128 (dst-side partials / T2)
  float* msgF  = B     + (size_t)F * 128;          // F*16
  float* msgV  = msgF  + (size_t)F * 16;           // N*16

  hipMemsetAsync(var_h, 0, (size_t)N * 64 * sizeof(float), stream);
  hipMemsetAsync(fac_h, 0, (size_t)F * 64 * sizeof(float), stream);

  const int gN = (N + 63) / 64;
  const int gF = (F + 63) / 64;
  const int gE = (E + 63) / 64;

  for (int step = 0; step < NSTEPS; ++step) {
    // ---- var -> factor ----
    k_dense<64, false, false><<<gN, 256, 0, stream>>>(var_h, m1w1,            nullptr, A, N);
    k_dense<64, false, false><<<gF, 256, 0, stream>>>(fac_h, m1w1 + 64 * 128, nullptr, B, F);
    k_edge<true><<<gE, 256, 0, stream>>>(A, B, v2f_src, v2f_dst, feat_v2f, m1b1,
                                         m1w2, m1b2, m1w3, m1b3, Qw, Qb, msgF, E);
    k_gru<<<gF, 256, 0, stream>>>(msgF, fac_h, g1wih, g1whh, g1bih, g1bhh, F);
    // ---- factor -> var ----
    k_dense<64, false, false><<<gF, 256, 0, stream>>>(fac_h, m2w1,            nullptr, A, F);
    k_dense<64, false, false><<<gN, 256, 0, stream>>>(var_h, m2w1 + 64 * 128, nullptr, B, N);
    hipMemsetAsync(msgV, 0, (size_t)N * 16 * sizeof(float), stream);
    k_edge<false><<<gE, 256, 0, stream>>>(A, B, f2v_src, f2v_dst, feat_f2v, m2b1,
                                          m2w2, m2b2, m2w3, m2b3, Qw, Qb, msgV, E);
    k_gru<<<gN, 256, 0, stream>>>(msgV, var_h, g2wih, g2whh, g2bih, g2bhh, N);
  }

  // ---- readout ----
  k_dense<64,  true, true><<<gN, 256, 0, stream>>>(var_h, row1, rob1, A, N);
  k_dense<128, true, true><<<gN, 256, 0, stream>>>(A,     row2, rob2, B, N);
  k_readout<<<(N + 255) / 256, 256, 0, stream>>>(B, row3, rob3, (float*)d_out, N);
}

// Round 2
// 1165.729 us; speedup vs baseline: 2.4406x; 2.4406x over previous
//
#include <hip/hip_runtime.h>

#define NSTEPS 10

typedef __attribute__((ext_vector_type(8))) short bf16x8;
typedef __attribute__((ext_vector_type(4))) short bf16x4;
typedef __attribute__((ext_vector_type(4))) float f32x4;

__device__ __forceinline__ float sigmoidf_(float x) { return 1.0f / (1.0f + __expf(-x)); }

// fp32 -> bf16 round-to-nearest-even
__device__ __forceinline__ short bf16_(float x) {
  union { float f; unsigned u; } c; c.f = x;
  unsigned r = (c.u + 0x7FFFu + ((c.u >> 16) & 1u)) >> 16;
  return (short)r;
}

__device__ __forceinline__ f32x4 mfma_16x16x32(bf16x8 a, bf16x8 b, f32x4 c) {
  return __builtin_amdgcn_mfma_f32_16x16x32_bf16(a, b, c, 0, 0, 0);
}

// ---------------------------------------------------------------------------
// k_pack: fp32 weights -> bf16 B-fragment chunks.
// Chunk = (nt, ks): 512 elems laid out so lane l=(q*16+n) loads its 8
// contiguous bf16 (B[k=ks*32+q*8+j][n_glob=nt*16+n]) with one dwordx4.
// Flat elem index within chunk: q*128 + n*8 + j.
// Last 5 chunks: q-transform matrices (K padded 16->32 with zeros):
//   B_t[kk][i] = Qw[t][i*16+kk] (t<4) or Qb[i*16+kk] (t==4), kk<16.
// ---------------------------------------------------------------------------
struct PackJob { const float* src; int N; int KS; int nchunks; };
struct PackArgs { PackJob jb[10]; const float* Qw; const float* Qb; };

__global__ __launch_bounds__(256) void k_pack(PackArgs a, short* __restrict__ out, int total) {
  const int g = blockIdx.x * 256 + threadIdx.x;
  if (g >= total) return;
  int c = g >> 9;
  const int r = g & 511;
  const int j = r & 7, n = (r >> 3) & 15, q = (r >> 7) & 3;
  float val = 0.f;
  bool done = false;
  #pragma unroll
  for (int ji = 0; ji < 10; ++ji) {
    if (!done && c < a.jb[ji].nchunks) {
      const int ks = c % a.jb[ji].KS;
      const int nt = c / a.jb[ji].KS;
      const int k = ks * 32 + q * 8 + j;
      val = a.jb[ji].src[(size_t)k * a.jb[ji].N + nt * 16 + n];
      done = true;
    }
    if (!done) c -= a.jb[ji].nchunks;
  }
  if (!done) {  // q chunks, c in [0,5)
    const int kk = q * 8 + j;
    val = 0.f;
    if (kk < 16) val = (c < 4) ? a.Qw[c * 256 + n * 16 + kk] : a.Qb[n * 16 + kk];
  }
  out[g] = bf16_(val);
}

// ---------------------------------------------------------------------------
// k_dense: C[rows,128] = act(X[rows,K] @ W[K,128] (+bias)), MFMA bf16.
// 64-row tile, 256 threads = 4 waves; wave w owns n-tiles {2w,2w+1};
// B operand entirely in registers from pre-swizzled frags.
// ---------------------------------------------------------------------------
template<int KS, bool RELU, bool BIAS>
__global__ __launch_bounds__(256) void k_dense(
    const float* __restrict__ X, const short* __restrict__ Wf,
    const float* __restrict__ bias, float* __restrict__ C, int rows)
{
  constexpr int K = KS * 32;
  constexpr int STR = K + 8;  // bf16 stride: 2-way bank alias (free), 16B-aligned rows
  __shared__ short Xs[64 * STR];
  const int t = threadIdx.x, lane = t & 63, wave = t >> 6;
  const int rbase = blockIdx.x * 64;

  // B frags (no LDS): 2 ntiles x KS ksteps
  bf16x8 b[2][KS];
  #pragma unroll
  for (int nt2 = 0; nt2 < 2; ++nt2)
    #pragma unroll
    for (int ks = 0; ks < KS; ++ks)
      b[nt2][ks] = ((const bf16x8*)Wf)[((wave * 2 + nt2) * KS + ks) * 64 + lane];

  // stage X tile as bf16 (A-operand row-major layout)
  {
    const int r = t >> 2, q4 = t & 3, rg = rbase + r;
    #pragma unroll
    for (int i = 0; i < K / 16; ++i) {
      const int c = q4 * 4 + i * 16;
      f32x4 v = {0.f, 0.f, 0.f, 0.f};
      if (rg < rows) v = *(const f32x4*)(X + (size_t)rg * K + c);
      bf16x4 h;
      h.x = bf16_(v.x); h.y = bf16_(v.y); h.z = bf16_(v.z); h.w = bf16_(v.w);
      *(bf16x4*)&Xs[r * STR + c] = h;
    }
  }
  __syncthreads();

  const int m = lane & 15, quad = lane >> 4;
  f32x4 acc[2][4] = {};
  #pragma unroll
  for (int ks = 0; ks < KS; ++ks) {
    bf16x8 afr[4];
    #pragma unroll
    for (int mt = 0; mt < 4; ++mt)
      afr[mt] = *(const bf16x8*)&Xs[(mt * 16 + m) * STR + ks * 32 + quad * 8];
    #pragma unroll
    for (int nt2 = 0; nt2 < 2; ++nt2)
      #pragma unroll
      for (int mt = 0; mt < 4; ++mt)
        acc[nt2][mt] = mfma_16x16x32(afr[mt], b[nt2][ks], acc[nt2][mt]);
  }

  // epilogue: C/D layout col=lane&15, row=quad*4+reg
  #pragma unroll
  for (int nt2 = 0; nt2 < 2; ++nt2) {
    const int col = (wave * 2 + nt2) * 16 + m;
    const float bv = BIAS ? bias[col] : 0.f;
    #pragma unroll
    for (int mt = 0; mt < 4; ++mt)
      #pragma unroll
      for (int rr = 0; rr < 4; ++rr) {
        const int rg = rbase + mt * 16 + quad * 4 + rr;
        if (rg < rows) {
          float v = acc[nt2][mt][rr] + bv;
          if (RELU) v = fmaxf(v, 0.f);
          C[(size_t)rg * 128 + col] = v;
        }
      }
  }
}

// ---------------------------------------------------------------------------
// k_edge (MFMA): per 64-edge tile:
//  h1 = relu(Pa[src]+Pb[dst]+b1)  -> LDS bf16 (A layout)
//  h2 = relu(h1 @ w2 + b2)        -> 32 MFMAs/wave, B in regs; back to LDS
//  m  = h2 @ w3 + b3              -> 4 MFMAs (wave = m-tile); -> LDS (K padded 32)
//  Y_t = m @ B_t (5 shared q mats)-> 5 MFMAs; mq = Y4 + feat . Y0..3
//  PAIRED: factor = edge>>1, consecutive rows are consecutive C-regs -> in-lane add
//  else: atomicAdd to outMsg[dst].
// ---------------------------------------------------------------------------
template<bool PAIRED>
__global__ __launch_bounds__(256) void k_edge(
    const float* __restrict__ Pa, const float* __restrict__ Pb,
    const int* __restrict__ src, const int* __restrict__ dst,
    const float* __restrict__ feat,
    const float* __restrict__ b1, const float* __restrict__ b2,
    const float* __restrict__ b3,
    const short* __restrict__ w2f, const short* __restrict__ w3f,
    const short* __restrict__ qf,
    float* __restrict__ outMsg, int E)
{
  __shared__ short h1s[64 * 136];   // 17408 B, reused for h2
  __shared__ short ms[64 * 40];     // 5120 B, m padded K 16->32 (upper zeroed)
  __shared__ float feats[64 * 4];
  __shared__ int sidx[64], didx[64];

  const int t = threadIdx.x, lane = t & 63, wave = t >> 6;
  const int e0 = blockIdx.x * 64;

  if (t < 64) {
    const int eg = e0 + t;
    sidx[t] = (eg < E) ? src[eg] : 0;
    didx[t] = (eg < E) ? dst[eg] : 0;
  }
  {
    const int e = t >> 2, k = t & 3;
    const int eg = e0 + e;
    feats[e * 4 + k] = (eg < E) ? feat[(size_t)eg * 4 + k] : 0.f;
  }
  // layer-2 B frags early (global, L2-cached; no LDS dependency)
  bf16x8 bw2[2][4];
  #pragma unroll
  for (int nt2 = 0; nt2 < 2; ++nt2)
    #pragma unroll
    for (int ks = 0; ks < 4; ++ks)
      bw2[nt2][ks] = ((const bf16x8*)w2f)[((wave * 2 + nt2) * 4 + ks) * 64 + lane];
  __syncthreads();

  // stage h1
  {
    const int r = t >> 2, q4 = t & 3;
    const float* pa = Pa + (size_t)sidx[r] * 128;
    const float* pb = Pb + (size_t)didx[r] * 128;
    #pragma unroll
    for (int i = 0; i < 8; ++i) {
      const int c = q4 * 4 + i * 16;
      const f32x4 va = *(const f32x4*)(pa + c);
      const f32x4 vb = *(const f32x4*)(pb + c);
      const f32x4 bb = *(const f32x4*)(b1 + c);
      bf16x4 h;
      h.x = bf16_(fmaxf(va.x + vb.x + bb.x, 0.f));
      h.y = bf16_(fmaxf(va.y + vb.y + bb.y, 0.f));
      h.z = bf16_(fmaxf(va.z + vb.z + bb.z, 0.f));
      h.w = bf16_(fmaxf(va.w + vb.w + bb.w, 0.f));
      *(bf16x4*)&h1s[r * 136 + c] = h;
    }
  }
  __syncthreads();

  const int m = lane & 15, quad = lane >> 4;

  // ---- layer 2 ----
  f32x4 acc2[2][4] = {};
  #pragma unroll
  for (int ks = 0; ks < 4; ++ks) {
    bf16x8 afr[4];
    #pragma unroll
    for (int mt = 0; mt < 4; ++mt)
      afr[mt] = *(const bf16x8*)&h1s[(mt * 16 + m) * 136 + ks * 32 + quad * 8];
    #pragma unroll
    for (int nt2 = 0; nt2 < 2; ++nt2)
      #pragma unroll
      for (int mt = 0; mt < 4; ++mt)
        acc2[nt2][mt] = mfma_16x16x32(afr[mt], bw2[nt2][ks], acc2[nt2][mt]);
  }
  __syncthreads();  // all h1 reads done before overwrite

  // h2 (bias+relu) back into h1s as bf16
  #pragma unroll
  for (int nt2 = 0; nt2 < 2; ++nt2) {
    const int col = (wave * 2 + nt2) * 16 + m;
    const float bv = b2[col];
    #pragma unroll
    for (int mt = 0; mt < 4; ++mt)
      #pragma unroll
      for (int rr = 0; rr < 4; ++rr)
        h1s[(mt * 16 + quad * 4 + rr) * 136 + col] =
            bf16_(fmaxf(acc2[nt2][mt][rr] + bv, 0.f));
  }
  // layer-3 / q B frags
  bf16x8 bw3[4];
  #pragma unroll
  for (int ks = 0; ks < 4; ++ks) bw3[ks] = ((const bf16x8*)w3f)[ks * 64 + lane];
  bf16x8 bq[5];
  #pragma unroll
  for (int tq = 0; tq < 5; ++tq) bq[tq] = ((const bf16x8*)qf)[tq * 64 + lane];
  __syncthreads();

  // ---- layer 3 (wave = m-tile) ----
  f32x4 acc3 = {};
  #pragma unroll
  for (int ks = 0; ks < 4; ++ks) {
    const bf16x8 afr = *(const bf16x8*)&h1s[(wave * 16 + m) * 136 + ks * 32 + quad * 8];
    acc3 = mfma_16x16x32(afr, bw3[ks], acc3);
  }
  const float b3v = b3[m];
  #pragma unroll
  for (int rr = 0; rr < 4; ++rr) {
    const int row = wave * 16 + quad * 4 + rr;
    ms[row * 40 + m] = bf16_(acc3[rr] + b3v);
    ms[row * 40 + 16 + m] = 0;  // zero pad k=16..31
  }
  __syncthreads();

  // ---- q transform: 5 shared GEMMs + feat blend ----
  f32x4 accY[5] = {};
  {
    const bf16x8 afr = *(const bf16x8*)&ms[(wave * 16 + m) * 40 + quad * 8];
    #pragma unroll
    for (int tq = 0; tq < 5; ++tq) accY[tq] = mfma_16x16x32(afr, bq[tq], accY[tq]);
  }
  float mq[4];
  #pragma unroll
  for (int rr = 0; rr < 4; ++rr) {
    const int row = wave * 16 + quad * 4 + rr;
    const f32x4 f = *(const f32x4*)&feats[row * 4];
    mq[rr] = accY[4][rr] + f.x * accY[0][rr] + f.y * accY[1][rr]
                         + f.z * accY[2][rr] + f.w * accY[3][rr];
  }

  if (PAIRED) {
    const int erow = wave * 16 + quad * 4;  // first of this lane's 4 rows (even)
    const int eg = e0 + erow;
    if (eg < E) {
      const int fb = eg >> 1;
      outMsg[(size_t)fb * 16 + m]       = mq[0] + mq[1];
      outMsg[(size_t)(fb + 1) * 16 + m] = mq[2] + mq[3];
    }
  } else {
    #pragma unroll
    for (int rr = 0; rr < 4; ++rr) {
      const int erow = wave * 16 + quad * 4 + rr;
      if (e0 + erow < E)
        atomicAdd(outMsg + (size_t)didx[erow] * 16 + m, mq[rr]);
    }
  }
}

// ---------------------------------------------------------------------------
// k_gru: unchanged scalar version (next round's target).
// ---------------------------------------------------------------------------
__global__ __launch_bounds__(256) void k_gru(
    const float* __restrict__ msg, float* __restrict__ h,
    const float* __restrict__ wih, const float* __restrict__ whh,
    const float* __restrict__ bih, const float* __restrict__ bhh, int rows)
{
  __shared__ float Wi[16 * 192];
  __shared__ float Wh[64 * 192];
  __shared__ float Hs[64 * 65];
  __shared__ float Ms[64 * 17];
  const int t = threadIdx.x;
  const int rbase = blockIdx.x * 64;

  #pragma unroll
  for (int i = 0; i < 3; ++i) {
    const int lin = t * 4 + i * 1024;
    *(float4*)(Wi + lin) = *(const float4*)(wih + lin);
  }
  #pragma unroll
  for (int i = 0; i < 12; ++i) {
    const int lin = t * 4 + i * 1024;
    *(float4*)(Wh + lin) = *(const float4*)(whh + lin);
  }
  {
    const int r = t >> 2, q = t & 3;
    const int rg = rbase + r;
    #pragma unroll
    for (int i = 0; i < 4; ++i) {
      const int c = q * 4 + i * 16;
      float4 v = make_float4(0.f, 0.f, 0.f, 0.f);
      if (rg < rows) v = *(const float4*)(h + (size_t)rg * 64 + c);
      Hs[r * 65 + c + 0] = v.x;
      Hs[r * 65 + c + 1] = v.y;
      Hs[r * 65 + c + 2] = v.z;
      Hs[r * 65 + c + 3] = v.w;
    }
    const int c = q * 4;
    float4 v = make_float4(0.f, 0.f, 0.f, 0.f);
    if (rg < rows) v = *(const float4*)(msg + (size_t)rg * 16 + c);
    Ms[r * 17 + c + 0] = v.x;
    Ms[r * 17 + c + 1] = v.y;
    Ms[r * 17 + c + 2] = v.z;
    Ms[r * 17 + c + 3] = v.w;
  }
  __syncthreads();

  const int r0 = (t >> 4) * 4;
  const int s0 = (t & 15) * 4;
  float ar[4][4], az[4][4], ani[4][4], anh[4][4];
  #pragma unroll
  for (int j = 0; j < 4; ++j)
    #pragma unroll
    for (int ss = 0; ss < 4; ++ss) { ar[j][ss] = 0.f; az[j][ss] = 0.f; ani[j][ss] = 0.f; anh[j][ss] = 0.f; }

  #pragma unroll 4
  for (int k = 0; k < 16; ++k) {
    const float4 wr = *(const float4*)(Wi + k * 192 + s0);
    const float4 wz = *(const float4*)(Wi + k * 192 + 64 + s0);
    const float4 wn = *(const float4*)(Wi + k * 192 + 128 + s0);
    #pragma unroll
    for (int j = 0; j < 4; ++j) {
      const float x = Ms[(r0 + j) * 17 + k];
      ar[j][0] = fmaf(x, wr.x, ar[j][0]); ar[j][1] = fmaf(x, wr.y, ar[j][1]);
      ar[j][2] = fmaf(x, wr.z, ar[j][2]); ar[j][3] = fmaf(x, wr.w, ar[j][3]);
      az[j][0] = fmaf(x, wz.x, az[j][0]); az[j][1] = fmaf(x, wz.y, az[j][1]);
      az[j][2] = fmaf(x, wz.z, az[j][2]); az[j][3] = fmaf(x, wz.w, az[j][3]);
      ani[j][0] = fmaf(x, wn.x, ani[j][0]); ani[j][1] = fmaf(x, wn.y, ani[j][1]);
      ani[j][2] = fmaf(x, wn.z, ani[j][2]); ani[j][3] = fmaf(x, wn.w, ani[j][3]);
    }
  }
  #pragma unroll 4
  for (int k = 0; k < 64; ++k) {
    const float4 wr = *(const float4*)(Wh + k * 192 + s0);
    const float4 wz = *(const float4*)(Wh + k * 192 + 64 + s0);
    const float4 wn = *(const float4*)(Wh + k * 192 + 128 + s0);
    #pragma unroll
    for (int j = 0; j < 4; ++j) {
      const float x = Hs[(r0 + j) * 65 + k];
      ar[j][0] = fmaf(x, wr.x, ar[j][0]); ar[j][1] = fmaf(x, wr.y, ar[j][1]);
      ar[j][2] = fmaf(x, wr.z, ar[j][2]); ar[j][3] = fmaf(x, wr.w, ar[j][3]);
      az[j][0] = fmaf(x, wz.x, az[j][0]); az[j][1] = fmaf(x, wz.y, az[j][1]);
      az[j][2] = fmaf(x, wz.z, az[j][2]); az[j][3] = fmaf(x, wz.w, az[j][3]);
      anh[j][0] = fmaf(x, wn.x, anh[j][0]); anh[j][1] = fmaf(x, wn.y, anh[j][1]);
      anh[j][2] = fmaf(x, wn.z, anh[j][2]); anh[j][3] = fmaf(x, wn.w, anh[j][3]);
    }
  }

  const float4 bir = *(const float4*)(bih + s0);
  const float4 bhr = *(const float4*)(bhh + s0);
  const float4 biz = *(const float4*)(bih + 64 + s0);
  const float4 bhz = *(const float4*)(bhh + 64 + s0);
  const float4 bin = *(const float4*)(bih + 128 + s0);
  const float4 bhn = *(const float4*)(bhh + 128 + s0);
  const float br[4] = {bir.x + bhr.x, bir.y + bhr.y, bir.z + bhr.z, bir.w + bhr.w};
  const float bz[4] = {biz.x + bhz.x, biz.y + bhz.y, biz.z + bhz.z, biz.w + bhz.w};
  const float bi[4] = {bin.x, bin.y, bin.z, bin.w};
  const float bh[4] = {bhn.x, bhn.y, bhn.z, bhn.w};

  #pragma unroll
  for (int j = 0; j < 4; ++j) {
    const int rg = rbase + r0 + j;
    if (rg >= rows) continue;
    float o[4];
    #pragma unroll
    for (int ss = 0; ss < 4; ++ss) {
      const float rr = sigmoidf_(ar[j][ss] + br[ss]);
      const float zz = sigmoidf_(az[j][ss] + bz[ss]);
      const float nn = tanhf(ani[j][ss] + bi[ss] + rr * (anh[j][ss] + bh[ss]));
      const float ho = Hs[(r0 + j) * 65 + s0 + ss];
      o[ss] = (1.f - zz) * nn + zz * ho;
    }
    *(float4*)(h + (size_t)rg * 64 + s0) = make_float4(o[0], o[1], o[2], o[3]);
  }
}

// ---------------------------------------------------------------------------
__global__ __launch_bounds__(256) void k_readout(
    const float* __restrict__ T2, const float* __restrict__ w3,
    const float* __restrict__ b3, float* __restrict__ out, int rows)
{
  const int n = blockIdx.x * 256 + threadIdx.x;
  if (n >= rows) return;
  float l0 = b3[0], l1 = b3[1];
  #pragma unroll 8
  for (int k = 0; k < 128; k += 4) {
    const float4 x = *(const float4*)(T2 + (size_t)n * 128 + k);
    l0 = fmaf(x.x, w3[(k + 0) * 2 + 0], l0);
    l0 = fmaf(x.y, w3[(k + 1) * 2 + 0], l0);
    l0 = fmaf(x.z, w3[(k + 2) * 2 + 0], l0);
    l0 = fmaf(x.w, w3[(k + 3) * 2 + 0], l0);
    l1 = fmaf(x.x, w3[(k + 0) * 2 + 1], l1);
    l1 = fmaf(x.y, w3[(k + 1) * 2 + 1], l1);
    l1 = fmaf(x.z, w3[(k + 2) * 2 + 1], l1);
    l1 = fmaf(x.w, w3[(k + 3) * 2 + 1], l1);
  }
  const float mx = fmaxf(l0, l1);
  const float e0 = __expf(l0 - mx), e1 = __expf(l1 - mx);
  const float inv = 1.f / (e0 + e1);
  out[(size_t)n * 2 + 0] = e0 * inv;
  out[(size_t)n * 2 + 1] = e1 * inv;
}

// ---------------------------------------------------------------------------
extern "C" void kernel_launch(void* const* d_in, const int* in_sizes, int n_in,
                              void* d_out, int out_size, void* d_ws, size_t ws_size,
                              hipStream_t stream)
{
  const int*   v2f_src  = (const int*)d_in[0];
  const int*   v2f_dst  = (const int*)d_in[1];
  const int*   f2v_src  = (const int*)d_in[2];
  const int*   f2v_dst  = (const int*)d_in[3];
  const float* feat_v2f = (const float*)d_in[4];
  const float* feat_f2v = (const float*)d_in[5];
  const float* Qw    = (const float*)d_in[8];
  const float* Qb    = (const float*)d_in[9];
  const float* m1w1  = (const float*)d_in[10];
  const float* m1b1  = (const float*)d_in[11];
  const float* m1w2  = (const float*)d_in[12];
  const float* m1b2  = (const float*)d_in[13];
  const float* m1w3  = (const float*)d_in[14];
  const float* m1b3  = (const float*)d_in[15];
  const float* m2w1  = (const float*)d_in[16];
  const float* m2b1  = (const float*)d_in[17];
  const float* m2w2  = (const float*)d_in[18];
  const float* m2b2  = (const float*)d_in[19];
  const float* m2w3  = (const float*)d_in[20];
  const float* m2b3  = (const float*)d_in[21];
  const float* g1wih = (const float*)d_in[22];
  const float* g1whh = (const float*)d_in[23];
  const float* g1bih = (const float*)d_in[24];
  const float* g1bhh = (const float*)d_in[25];
  const float* g2wih = (const float*)d_in[26];
  const float* g2whh = (const float*)d_in[27];
  const float* g2bih = (const float*)d_in[28];
  const float* g2bhh = (const float*)d_in[29];
  const float* row1  = (const float*)d_in[30];
  const float* rob1  = (const float*)d_in[31];
  const float* row2  = (const float*)d_in[32];
  const float* rob2  = (const float*)d_in[33];
  const float* row3  = (const float*)d_in[34];
  const float* rob3  = (const float*)d_in[35];

  const int E = in_sizes[0];
  const int N = out_size / 2;
  const int F = E / 2;

  // fp32 workspace
  float* ws    = (float*)d_ws;
  float* var_h = ws;                               // N*64
  float* fac_h = var_h + (size_t)N * 64;           // F*64
  float* A     = fac_h + (size_t)F * 64;           // F*128
  float* B     = A     + (size_t)F * 128;          // F*128
  float* msgF  = B     + (size_t)F * 128;          // F*16
  float* msgV  = msgF  + (size_t)F * 16;           // N*16
  // bf16 fragment region (16B aligned: all prior sizes are multiples of 8 floats)
  short* wb    = (short*)(msgV + (size_t)N * 16);

  // chunk offsets (1 chunk = 512 bf16)
  const int C_W2A = 0,  C_W2B = 32, C_W3A = 64, C_W3B = 68;
  const int C_W1AS = 72, C_W1AD = 88, C_W1BS = 104, C_W1BD = 120;
  const int C_RO1 = 136, C_RO2 = 152, C_Q = 184;
  const int TOTAL_CHUNKS = 189;

  short* PB_w2a  = wb + C_W2A  * 512;
  short* PB_w2b  = wb + C_W2B  * 512;
  short* PB_w3a  = wb + C_W3A  * 512;
  short* PB_w3b  = wb + C_W3B  * 512;
  short* PB_w1as = wb + C_W1AS * 512;
  short* PB_w1ad = wb + C_W1AD * 512;
  short* PB_w1bs = wb + C_W1BS * 512;
  short* PB_w1bd = wb + C_W1BD * 512;
  short* PB_ro1  = wb + C_RO1  * 512;
  short* PB_ro2  = wb + C_RO2  * 512;
  short* PB_q    = wb + C_Q    * 512;

  hipMemsetAsync(var_h, 0, (size_t)N * 64 * sizeof(float), stream);
  hipMemsetAsync(fac_h, 0, (size_t)F * 64 * sizeof(float), stream);

  // ---- pack weights to bf16 fragments ----
  PackArgs pa;
  pa.jb[0] = {m1w2,              128, 4, 32};   // C_W2A
  pa.jb[1] = {m2w2,              128, 4, 32};   // C_W2B
  pa.jb[2] = {m1w3,               16, 4,  4};   // C_W3A
  pa.jb[3] = {m2w3,               16, 4,  4};   // C_W3B
  pa.jb[4] = {m1w1,              128, 2, 16};   // C_W1AS (rows 0..63: var/src side)
  pa.jb[5] = {m1w1 + 64 * 128,   128, 2, 16};   // C_W1AD (rows 64..127: fac/dst side)
  pa.jb[6] = {m2w1,              128, 2, 16};   // C_W1BS (fac/src side)
  pa.jb[7] = {m2w1 + 64 * 128,   128, 2, 16};   // C_W1BD (var/dst side)
  pa.jb[8] = {row1,              128, 2, 16};   // C_RO1
  pa.jb[9] = {row2,              128, 4, 32};   // C_RO2
  pa.Qw = Qw; pa.Qb = Qb;
  const int packTotal = TOTAL_CHUNKS * 512;
  k_pack<<<(packTotal + 255) / 256, 256, 0, stream>>>(pa, wb, packTotal);

  const int gN = (N + 63) / 64;
  const int gF = (F + 63) / 64;
  const int gE = (E + 63) / 64;

  for (int step = 0; step < NSTEPS; ++step) {
    // ---- var -> factor ----
    k_dense<2, false, false><<<gN, 256, 0, stream>>>(var_h, PB_w1as, nullptr, A, N);
    k_dense<2, false, false><<<gF, 256, 0, stream>>>(fac_h, PB_w1ad, nullptr, B, F);
    k_edge<true><<<gE, 256, 0, stream>>>(A, B, v2f_src, v2f_dst, feat_v2f,
                                         m1b1, m1b2, m1b3, PB_w2a, PB_w3a, PB_q, msgF, E);
    k_gru<<<gF, 256, 0, stream>>>(msgF, fac_h, g1wih, g1whh, g1bih, g1bhh, F);
    // ---- factor -> var ----
    k_dense<2, false, false><<<gF, 256, 0, stream>>>(fac_h, PB_w1bs, nullptr, A, F);
    k_dense<2, false, false><<<gN, 256, 0, stream>>>(var_h, PB_w1bd, nullptr, B, N);
    hipMemsetAsync(msgV, 0, (size_t)N * 16 * sizeof(float), stream);
    k_edge<false><<<gE, 256, 0, stream>>>(A, B, f2v_src, f2v_dst, feat_f2v,
                                          m2b1, m2b2, m2b3, PB_w2b, PB_w3b, PB_q, msgV, E);
    k_gru<<<gN, 256, 0, stream>>>(msgV, var_h, g2wih, g2whh, g2bih, g2bhh, N);
  }

  // ---- readout ----
  k_dense<2, true, true><<<gN, 256, 0, stream>>>(var_h, PB_ro1, rob1, A, N);
  k_dense<4, true, true><<<gN, 256, 0, stream>>>(A,     PB_ro2, rob2, B, N);
  k_readout<<<(N + 255) / 256, 256, 0, stream>>>(B, row3, rob3, (float*)d_out, N);
}

// Round 3
// 825.145 us; speedup vs baseline: 3.4479x; 1.4128x over previous
//
#include <hip/hip_runtime.h>

#define NSTEPS 10

typedef __attribute__((ext_vector_type(8))) short bf16x8;
typedef __attribute__((ext_vector_type(4))) short bf16x4;
typedef __attribute__((ext_vector_type(4))) float f32x4;

__device__ __forceinline__ float sigmoidf_(float x) { return 1.0f / (1.0f + __expf(-x)); }
__device__ __forceinline__ float tanh_fast(float x) {
  const float e = __expf(2.f * x);
  return 1.f - 2.f / (e + 1.f);
}

// fp32 -> bf16 round-to-nearest-even (used in one-time weight pack only)
__device__ __forceinline__ short bf16_(float x) {
  union { float f; unsigned u; } c; c.f = x;
  unsigned r = (c.u + 0x7FFFu + ((c.u >> 16) & 1u)) >> 16;
  return (short)r;
}
// fast paths (round-half-up, <=0.5 ulp): 1 add/elem + 1 perm/2 elems
__device__ __forceinline__ unsigned pk2_(float a, float b) {
  union { float f; unsigned u; } ca, cb; ca.f = a; cb.f = b;
  return __builtin_amdgcn_perm(cb.u + 0x8000u, ca.u + 0x8000u, 0x07060302u);
}
__device__ __forceinline__ short pk1_(float a) {
  union { float f; unsigned u; } c; c.f = a;
  return (short)((c.u + 0x8000u) >> 16);
}
// packed bf16 pair -> floats
__device__ __forceinline__ float lo_(unsigned u) { union { unsigned u; float f; } c; c.u = u << 16; return c.f; }
__device__ __forceinline__ float hi_(unsigned u) { union { unsigned u; float f; } c; c.u = u & 0xffff0000u; return c.f; }

__device__ __forceinline__ f32x4 mfma_16x16x32(bf16x8 a, bf16x8 b, f32x4 c) {
  return __builtin_amdgcn_mfma_f32_16x16x32_bf16(a, b, c, 0, 0, 0);
}

// ---------------------------------------------------------------------------
// k_pack: fp32 weights -> bf16 B-fragment chunks (one-time).
// Chunk (nt,ks), 512 elems: flat idx = q*128 + n*8 + j holds B[k=ks*32+q*8+j][nt*16+n].
// After 10 generic jobs: 5 q-chunks, then 2 x 48 GRU chunks (256 cols = [r|z|in|hn], K=96).
// ---------------------------------------------------------------------------
struct PackJob { const float* src; int N; int KS; int nchunks; };
struct PackArgs {
  PackJob jb[10];
  const float* Qw; const float* Qb;
  const float* g1wih; const float* g1whh;
  const float* g2wih; const float* g2whh;
};

__global__ __launch_bounds__(256) void k_pack(PackArgs a, short* __restrict__ out, int total) {
  const int g = blockIdx.x * 256 + threadIdx.x;
  if (g >= total) return;
  int c = g >> 9;
  const int r = g & 511;
  const int j = r & 7, n = (r >> 3) & 15, q = (r >> 7) & 3;
  const int kq = q * 8 + j;
  float val = 0.f;
  bool done = false;
  #pragma unroll
  for (int ji = 0; ji < 10; ++ji) {
    if (!done && c < a.jb[ji].nchunks) {
      const int ks = c % a.jb[ji].KS;
      const int nt = c / a.jb[ji].KS;
      const int k = ks * 32 + kq;
      val = a.jb[ji].src[(size_t)k * a.jb[ji].N + nt * 16 + n];
      done = true;
    }
    if (!done) c -= a.jb[ji].nchunks;
  }
  if (!done) {
    if (c < 5) {  // q-transform chunks (K padded 16->32)
      val = 0.f;
      if (kq < 16) val = (c < 4) ? a.Qw[c * 256 + n * 16 + kq] : a.Qb[n * 16 + kq];
    } else {      // GRU chunks
      c -= 5;
      const float* wih = (c < 48) ? a.g1wih : a.g2wih;
      const float* whh = (c < 48) ? a.g1whh : a.g2whh;
      if (c >= 48) c -= 48;
      const int nt = c / 3, ks = c % 3;
      const int k = ks * 32 + kq;            // 0..95
      const int ng = nt * 16 + n;            // 0..255
      const int gate = ng >> 6, s = ng & 63;
      val = 0.f;
      if (gate == 0) {        // r
        if (k < 16) val = wih[k * 192 + s];
        else if (k < 80) val = whh[(k - 16) * 192 + s];
      } else if (gate == 1) { // z
        if (k < 16) val = wih[k * 192 + 64 + s];
        else if (k < 80) val = whh[(k - 16) * 192 + 64 + s];
      } else if (gate == 2) { // i_n (wih only)
        if (k < 16) val = wih[k * 192 + 128 + s];
      } else {                // h_n (whh only)
        if (k >= 16 && k < 80) val = whh[(k - 16) * 192 + 128 + s];
      }
    }
  }
  out[g] = bf16_(val);
}

// ---------------------------------------------------------------------------
// k_dense2: two layer-1 partial GEMMs (K=64) in one dispatch, bf16 output.
// job0: blocks [0,g0)   : C0[rows0,128] = X0 @ W0
// job1: blocks [g0,...) : C1[rows1,128] = X1 @ W1 ; optionally zero msg rows.
// ---------------------------------------------------------------------------
__global__ __launch_bounds__(256) void k_dense2(
    const float* __restrict__ X0, const short* __restrict__ W0, short* __restrict__ C0,
    int rows0, int g0,
    const float* __restrict__ X1, const short* __restrict__ W1, short* __restrict__ C1,
    int rows1, float* __restrict__ zeroPtr)
{
  constexpr int KS = 2, K = 64, STR = K + 8;
  __shared__ short Xs[64 * STR];
  const int t = threadIdx.x, lane = t & 63, wave = t >> 6;

  const float* X; const short* Wf; short* C; int rows, rbase;
  if ((int)blockIdx.x < g0) {
    X = X0; Wf = W0; C = C0; rows = rows0; rbase = blockIdx.x * 64;
  } else {
    X = X1; Wf = W1; C = C1; rows = rows1; rbase = ((int)blockIdx.x - g0) * 64;
    if (zeroPtr) {
      const int zr = rbase + (t >> 2);
      if (zr < rows1) {
        f32x4 z = {0.f, 0.f, 0.f, 0.f};
        *(f32x4*)(zeroPtr + (size_t)zr * 16 + (t & 3) * 4) = z;
      }
    }
  }

  bf16x8 b[2][KS];
  #pragma unroll
  for (int nt2 = 0; nt2 < 2; ++nt2)
    #pragma unroll
    for (int ks = 0; ks < KS; ++ks)
      b[nt2][ks] = ((const bf16x8*)Wf)[((wave * 2 + nt2) * KS + ks) * 64 + lane];

  {
    const int r = t >> 2, q4 = t & 3, rg = rbase + r;
    #pragma unroll
    for (int i = 0; i < K / 16; ++i) {
      const int cc = q4 * 4 + i * 16;
      f32x4 v = {0.f, 0.f, 0.f, 0.f};
      if (rg < rows) v = *(const f32x4*)(X + (size_t)rg * K + cc);
      *(unsigned*)&Xs[r * STR + cc]     = pk2_(v.x, v.y);
      *(unsigned*)&Xs[r * STR + cc + 2] = pk2_(v.z, v.w);
    }
  }
  __syncthreads();

  const int m = lane & 15, quad = lane >> 4;
  f32x4 acc[2][4] = {};
  #pragma unroll
  for (int ks = 0; ks < KS; ++ks) {
    bf16x8 afr[4];
    #pragma unroll
    for (int mt = 0; mt < 4; ++mt)
      afr[mt] = *(const bf16x8*)&Xs[(mt * 16 + m) * STR + ks * 32 + quad * 8];
    #pragma unroll
    for (int nt2 = 0; nt2 < 2; ++nt2)
      #pragma unroll
      for (int mt = 0; mt < 4; ++mt)
        acc[nt2][mt] = mfma_16x16x32(afr[mt], b[nt2][ks], acc[nt2][mt]);
  }

  #pragma unroll
  for (int nt2 = 0; nt2 < 2; ++nt2) {
    const int col = (wave * 2 + nt2) * 16 + m;
    #pragma unroll
    for (int mt = 0; mt < 4; ++mt)
      #pragma unroll
      for (int rr = 0; rr < 4; ++rr) {
        const int rg = rbase + mt * 16 + quad * 4 + rr;
        if (rg < rows) C[(size_t)rg * 128 + col] = pk1_(acc[nt2][mt][rr]);
      }
  }
}

// ---------------------------------------------------------------------------
// k_dense: fp32-out GEMM w/ bias+relu (readout layers only).
// ---------------------------------------------------------------------------
template<int KS>
__global__ __launch_bounds__(256) void k_dense(
    const float* __restrict__ X, const short* __restrict__ Wf,
    const float* __restrict__ bias, float* __restrict__ C, int rows)
{
  constexpr int K = KS * 32;
  constexpr int STR = K + 8;
  __shared__ short Xs[64 * STR];
  const int t = threadIdx.x, lane = t & 63, wave = t >> 6;
  const int rbase = blockIdx.x * 64;

  bf16x8 b[2][KS];
  #pragma unroll
  for (int nt2 = 0; nt2 < 2; ++nt2)
    #pragma unroll
    for (int ks = 0; ks < KS; ++ks)
      b[nt2][ks] = ((const bf16x8*)Wf)[((wave * 2 + nt2) * KS + ks) * 64 + lane];

  {
    const int r = t >> 2, q4 = t & 3, rg = rbase + r;
    #pragma unroll
    for (int i = 0; i < K / 16; ++i) {
      const int cc = q4 * 4 + i * 16;
      f32x4 v = {0.f, 0.f, 0.f, 0.f};
      if (rg < rows) v = *(const f32x4*)(X + (size_t)rg * K + cc);
      *(unsigned*)&Xs[r * STR + cc]     = pk2_(v.x, v.y);
      *(unsigned*)&Xs[r * STR + cc + 2] = pk2_(v.z, v.w);
    }
  }
  __syncthreads();

  const int m = lane & 15, quad = lane >> 4;
  f32x4 acc[2][4] = {};
  #pragma unroll
  for (int ks = 0; ks < KS; ++ks) {
    bf16x8 afr[4];
    #pragma unroll
    for (int mt = 0; mt < 4; ++mt)
      afr[mt] = *(const bf16x8*)&Xs[(mt * 16 + m) * STR + ks * 32 + quad * 8];
    #pragma unroll
    for (int nt2 = 0; nt2 < 2; ++nt2)
      #pragma unroll
      for (int mt = 0; mt < 4; ++mt)
        acc[nt2][mt] = mfma_16x16x32(afr[mt], b[nt2][ks], acc[nt2][mt]);
  }

  #pragma unroll
  for (int nt2 = 0; nt2 < 2; ++nt2) {
    const int col = (wave * 2 + nt2) * 16 + m;
    const float bv = bias[col];
    #pragma unroll
    for (int mt = 0; mt < 4; ++mt)
      #pragma unroll
      for (int rr = 0; rr < 4; ++rr) {
        const int rg = rbase + mt * 16 + quad * 4 + rr;
        if (rg < rows) C[(size_t)rg * 128 + col] = fmaxf(acc[nt2][mt][rr] + bv, 0.f);
      }
  }
}

// ---------------------------------------------------------------------------
// k_edge (MFMA, bf16 partial inputs)
// ---------------------------------------------------------------------------
template<bool PAIRED>
__global__ __launch_bounds__(256) void k_edge(
    const short* __restrict__ Pa, const short* __restrict__ Pb,
    const int* __restrict__ src, const int* __restrict__ dst,
    const float* __restrict__ feat,
    const float* __restrict__ b1, const float* __restrict__ b2,
    const float* __restrict__ b3,
    const short* __restrict__ w2f, const short* __restrict__ w3f,
    const short* __restrict__ qf,
    float* __restrict__ outMsg, int E)
{
  __shared__ short h1s[64 * 136];
  __shared__ short ms[64 * 40];
  __shared__ float feats[64 * 4];
  __shared__ int sidx[64], didx[64];

  const int t = threadIdx.x, lane = t & 63, wave = t >> 6;
  const int e0 = blockIdx.x * 64;

  if (t < 64) {
    const int eg = e0 + t;
    sidx[t] = (eg < E) ? src[eg] : 0;
    didx[t] = (eg < E) ? dst[eg] : 0;
  }
  {
    const int e = t >> 2, k = t & 3;
    const int eg = e0 + e;
    feats[e * 4 + k] = (eg < E) ? feat[(size_t)eg * 4 + k] : 0.f;
  }
  bf16x8 bw2[2][4];
  #pragma unroll
  for (int nt2 = 0; nt2 < 2; ++nt2)
    #pragma unroll
    for (int ks = 0; ks < 4; ++ks)
      bw2[nt2][ks] = ((const bf16x8*)w2f)[((wave * 2 + nt2) * 4 + ks) * 64 + lane];
  __syncthreads();

  // stage h1 = relu(Pa[src]+Pb[dst]+b1), bf16 in, bf16 out
  {
    const int r = t >> 2, q4 = t & 3;
    const bool ok = (e0 + r) < E;
    const short* pa = Pa + (size_t)sidx[r] * 128;
    const short* pb = Pb + (size_t)didx[r] * 128;
    #pragma unroll
    for (int i = 0; i < 4; ++i) {
      const int col = (q4 + i * 4) * 8;
      uint4 o = make_uint4(0u, 0u, 0u, 0u);
      if (ok) {
        const uint4 ua = *(const uint4*)(pa + col);
        const uint4 ub = *(const uint4*)(pb + col);
        const f32x4 ba = *(const f32x4*)(b1 + col);
        const f32x4 bb = *(const f32x4*)(b1 + col + 4);
        o.x = pk2_(fmaxf(lo_(ua.x) + lo_(ub.x) + ba.x, 0.f),
                   fmaxf(hi_(ua.x) + hi_(ub.x) + ba.y, 0.f));
        o.y = pk2_(fmaxf(lo_(ua.y) + lo_(ub.y) + ba.z, 0.f),
                   fmaxf(hi_(ua.y) + hi_(ub.y) + ba.w, 0.f));
        o.z = pk2_(fmaxf(lo_(ua.z) + lo_(ub.z) + bb.x, 0.f),
                   fmaxf(hi_(ua.z) + hi_(ub.z) + bb.y, 0.f));
        o.w = pk2_(fmaxf(lo_(ua.w) + lo_(ub.w) + bb.z, 0.f),
                   fmaxf(hi_(ua.w) + hi_(ub.w) + bb.w, 0.f));
      }
      *(uint4*)&h1s[r * 136 + col] = o;
    }
  }
  __syncthreads();

  const int m = lane & 15, quad = lane >> 4;

  // ---- layer 2 ----
  f32x4 acc2[2][4] = {};
  #pragma unroll
  for (int ks = 0; ks < 4; ++ks) {
    bf16x8 afr[4];
    #pragma unroll
    for (int mt = 0; mt < 4; ++mt)
      afr[mt] = *(const bf16x8*)&h1s[(mt * 16 + m) * 136 + ks * 32 + quad * 8];
    #pragma unroll
    for (int nt2 = 0; nt2 < 2; ++nt2)
      #pragma unroll
      for (int mt = 0; mt < 4; ++mt)
        acc2[nt2][mt] = mfma_16x16x32(afr[mt], bw2[nt2][ks], acc2[nt2][mt]);
  }
  __syncthreads();

  // h2 back to LDS (bias+relu)
  #pragma unroll
  for (int nt2 = 0; nt2 < 2; ++nt2) {
    const int col = (wave * 2 + nt2) * 16 + m;
    const float bv = b2[col];
    #pragma unroll
    for (int mt = 0; mt < 4; ++mt)
      #pragma unroll
      for (int rr = 0; rr < 4; ++rr)
        h1s[(mt * 16 + quad * 4 + rr) * 136 + col] =
            pk1_(fmaxf(acc2[nt2][mt][rr] + bv, 0.f));
  }
  bf16x8 bw3[4];
  #pragma unroll
  for (int ks = 0; ks < 4; ++ks) bw3[ks] = ((const bf16x8*)w3f)[ks * 64 + lane];
  bf16x8 bq[5];
  #pragma unroll
  for (int tq = 0; tq < 5; ++tq) bq[tq] = ((const bf16x8*)qf)[tq * 64 + lane];
  __syncthreads();

  // ---- layer 3 (wave = m-tile) ----
  f32x4 acc3 = {};
  #pragma unroll
  for (int ks = 0; ks < 4; ++ks) {
    const bf16x8 afr = *(const bf16x8*)&h1s[(wave * 16 + m) * 136 + ks * 32 + quad * 8];
    acc3 = mfma_16x16x32(afr, bw3[ks], acc3);
  }
  const float b3v = b3[m];
  #pragma unroll
  for (int rr = 0; rr < 4; ++rr) {
    const int row = wave * 16 + quad * 4 + rr;
    ms[row * 40 + m] = pk1_(acc3[rr] + b3v);
    ms[row * 40 + 16 + m] = 0;
  }
  __syncthreads();

  // ---- q transform ----
  f32x4 accY[5] = {};
  {
    const bf16x8 afr = *(const bf16x8*)&ms[(wave * 16 + m) * 40 + quad * 8];
    #pragma unroll
    for (int tq = 0; tq < 5; ++tq) accY[tq] = mfma_16x16x32(afr, bq[tq], accY[tq]);
  }
  float mq[4];
  #pragma unroll
  for (int rr = 0; rr < 4; ++rr) {
    const int row = wave * 16 + quad * 4 + rr;
    const f32x4 f = *(const f32x4*)&feats[row * 4];
    mq[rr] = accY[4][rr] + f.x * accY[0][rr] + f.y * accY[1][rr]
                         + f.z * accY[2][rr] + f.w * accY[3][rr];
  }

  if (PAIRED) {
    const int erow = wave * 16 + quad * 4;
    const int eg = e0 + erow;
    if (eg < E) {
      const int fb = eg >> 1;
      outMsg[(size_t)fb * 16 + m]       = mq[0] + mq[1];
      outMsg[(size_t)(fb + 1) * 16 + m] = mq[2] + mq[3];
    }
  } else {
    #pragma unroll
    for (int rr = 0; rr < 4; ++rr) {
      const int erow = wave * 16 + quad * 4 + rr;
      if (e0 + erow < E)
        atomicAdd(outMsg + (size_t)didx[erow] * 16 + m, mq[rr]);
    }
  }
}

// ---------------------------------------------------------------------------
// k_gru (MFMA): gates GEMM [64 x 96] @ [96 x 256] ([r|z|in|hn]); wave = row-tile
// so all 4 gates of (row,s) sit in one lane's acc -> in-register epilogue.
// ---------------------------------------------------------------------------
__global__ __launch_bounds__(256) void k_gru(
    const float* __restrict__ msg, float* __restrict__ h,
    const short* __restrict__ Wf,
    const float* __restrict__ bih, const float* __restrict__ bhh, int rows)
{
  __shared__ short As[64 * 104];   // [msg(16) | h(64) | 0(16)] + 8 pad
  const int t = threadIdx.x, lane = t & 63, wave = t >> 6;
  const int rbase = blockIdx.x * 64;

  {
    const int r = t >> 2, q4 = t & 3, rg = rbase + r;
    #pragma unroll
    for (int i = 0; i < 6; ++i) {
      const int c = (q4 + i * 4) * 4;   // 0..92 step 4
      f32x4 v = {0.f, 0.f, 0.f, 0.f};
      if (rg < rows) {
        if (c < 16)      v = *(const f32x4*)(msg + (size_t)rg * 16 + c);
        else if (c < 80) v = *(const f32x4*)(h + (size_t)rg * 64 + (c - 16));
      }
      *(unsigned*)&As[r * 104 + c]     = pk2_(v.x, v.y);
      *(unsigned*)&As[r * 104 + c + 2] = pk2_(v.z, v.w);
    }
  }
  __syncthreads();

  const int m = lane & 15, quad = lane >> 4;
  f32x4 acc[16] = {};
  #pragma unroll
  for (int ks = 0; ks < 3; ++ks) {
    const bf16x8 a = *(const bf16x8*)&As[(wave * 16 + m) * 104 + ks * 32 + quad * 8];
    #pragma unroll
    for (int nt = 0; nt < 16; ++nt) {
      const bf16x8 b = ((const bf16x8*)Wf)[(nt * 3 + ks) * 64 + lane];
      acc[nt] = mfma_16x16x32(a, b, acc[nt]);
    }
  }

  #pragma unroll
  for (int nt = 0; nt < 4; ++nt) {
    const int s = nt * 16 + m;
    const float br  = bih[s] + bhh[s];
    const float bz  = bih[64 + s] + bhh[64 + s];
    const float bin = bih[128 + s];
    const float bhn = bhh[128 + s];
    #pragma unroll
    for (int reg = 0; reg < 4; ++reg) {
      const int rg = rbase + wave * 16 + quad * 4 + reg;
      if (rg < rows) {
        const float ho = h[(size_t)rg * 64 + s];
        const float rr = sigmoidf_(acc[nt][reg] + br);
        const float zz = sigmoidf_(acc[4 + nt][reg] + bz);
        const float nn = tanh_fast(acc[8 + nt][reg] + bin + rr * (acc[12 + nt][reg] + bhn));
        h[(size_t)rg * 64 + s] = (1.f - zz) * nn + zz * ho;
      }
    }
  }
}

// ---------------------------------------------------------------------------
__global__ __launch_bounds__(256) void k_readout(
    const float* __restrict__ T2, const float* __restrict__ w3,
    const float* __restrict__ b3, float* __restrict__ out, int rows)
{
  const int n = blockIdx.x * 256 + threadIdx.x;
  if (n >= rows) return;
  float l0 = b3[0], l1 = b3[1];
  #pragma unroll 8
  for (int k = 0; k < 128; k += 4) {
    const float4 x = *(const float4*)(T2 + (size_t)n * 128 + k);
    l0 = fmaf(x.x, w3[(k + 0) * 2 + 0], l0);
    l0 = fmaf(x.y, w3[(k + 1) * 2 + 0], l0);
    l0 = fmaf(x.z, w3[(k + 2) * 2 + 0], l0);
    l0 = fmaf(x.w, w3[(k + 3) * 2 + 0], l0);
    l1 = fmaf(x.x, w3[(k + 0) * 2 + 1], l1);
    l1 = fmaf(x.y, w3[(k + 1) * 2 + 1], l1);
    l1 = fmaf(x.z, w3[(k + 2) * 2 + 1], l1);
    l1 = fmaf(x.w, w3[(k + 3) * 2 + 1], l1);
  }
  const float mx = fmaxf(l0, l1);
  const float e0 = __expf(l0 - mx), e1 = __expf(l1 - mx);
  const float inv = 1.f / (e0 + e1);
  out[(size_t)n * 2 + 0] = e0 * inv;
  out[(size_t)n * 2 + 1] = e1 * inv;
}

// ---------------------------------------------------------------------------
extern "C" void kernel_launch(void* const* d_in, const int* in_sizes, int n_in,
                              void* d_out, int out_size, void* d_ws, size_t ws_size,
                              hipStream_t stream)
{
  const int*   v2f_src  = (const int*)d_in[0];
  const int*   v2f_dst  = (const int*)d_in[1];
  const int*   f2v_src  = (const int*)d_in[2];
  const int*   f2v_dst  = (const int*)d_in[3];
  const float* feat_v2f = (const float*)d_in[4];
  const float* feat_f2v = (const float*)d_in[5];
  const float* Qw    = (const float*)d_in[8];
  const float* Qb    = (const float*)d_in[9];
  const float* m1w1  = (const float*)d_in[10];
  const float* m1b1  = (const float*)d_in[11];
  const float* m1w2  = (const float*)d_in[12];
  const float* m1b2  = (const float*)d_in[13];
  const float* m1w3  = (const float*)d_in[14];
  const float* m1b3  = (const float*)d_in[15];
  const float* m2w1  = (const float*)d_in[16];
  const float* m2b1  = (const float*)d_in[17];
  const float* m2w2  = (const float*)d_in[18];
  const float* m2b2  = (const float*)d_in[19];
  const float* m2w3  = (const float*)d_in[20];
  const float* m2b3  = (const float*)d_in[21];
  const float* g1wih = (const float*)d_in[22];
  const float* g1whh = (const float*)d_in[23];
  const float* g1bih = (const float*)d_in[24];
  const float* g1bhh = (const float*)d_in[25];
  const float* g2wih = (const float*)d_in[26];
  const float* g2whh = (const float*)d_in[27];
  const float* g2bih = (const float*)d_in[28];
  const float* g2bhh = (const float*)d_in[29];
  const float* row1  = (const float*)d_in[30];
  const float* rob1  = (const float*)d_in[31];
  const float* row2  = (const float*)d_in[32];
  const float* rob2  = (const float*)d_in[33];
  const float* row3  = (const float*)d_in[34];
  const float* rob3  = (const float*)d_in[35];

  const int E = in_sizes[0];
  const int N = out_size / 2;
  const int F = E / 2;

  // ---- workspace layout ----
  float* ws    = (float*)d_ws;
  float* var_h = ws;                               // N*64 f32
  float* fac_h = var_h + (size_t)N * 64;           // F*64 f32
  float* msgF  = fac_h + (size_t)F * 64;           // F*16 f32
  float* msgV  = msgF  + (size_t)F * 16;           // N*16 f32
  float* T1    = msgV  + (size_t)N * 16;           // N*128 f32
  float* T2    = T1    + (size_t)N * 128;          // N*128 f32
  short* Abuf  = (short*)(T2 + (size_t)N * 128);   // F*128 bf16
  short* Bbuf  = Abuf + (size_t)F * 128;           // F*128 bf16
  short* wb    = Bbuf + (size_t)F * 128;           // packed weights

  // chunk offsets (1 chunk = 512 bf16)
  const int C_W2A = 0,  C_W2B = 32, C_W3A = 64, C_W3B = 68;
  const int C_W1AS = 72, C_W1AD = 88, C_W1BS = 104, C_W1BD = 120;
  const int C_RO1 = 136, C_RO2 = 152, C_Q = 184, C_G1 = 189, C_G2 = 237;
  const int TOTAL_CHUNKS = 285;

  short* PB_w2a  = wb + C_W2A  * 512;
  short* PB_w2b  = wb + C_W2B  * 512;
  short* PB_w3a  = wb + C_W3A  * 512;
  short* PB_w3b  = wb + C_W3B  * 512;
  short* PB_w1as = wb + C_W1AS * 512;
  short* PB_w1ad = wb + C_W1AD * 512;
  short* PB_w1bs = wb + C_W1BS * 512;
  short* PB_w1bd = wb + C_W1BD * 512;
  short* PB_ro1  = wb + C_RO1  * 512;
  short* PB_ro2  = wb + C_RO2  * 512;
  short* PB_q    = wb + C_Q    * 512;
  short* PB_g1   = wb + C_G1   * 512;
  short* PB_g2   = wb + C_G2   * 512;

  hipMemsetAsync(var_h, 0, (size_t)N * 64 * sizeof(float), stream);
  hipMemsetAsync(fac_h, 0, (size_t)F * 64 * sizeof(float), stream);

  PackArgs pa;
  pa.jb[0] = {m1w2,            128, 4, 32};
  pa.jb[1] = {m2w2,            128, 4, 32};
  pa.jb[2] = {m1w3,             16, 4,  4};
  pa.jb[3] = {m2w3,             16, 4,  4};
  pa.jb[4] = {m1w1,            128, 2, 16};
  pa.jb[5] = {m1w1 + 64 * 128, 128, 2, 16};
  pa.jb[6] = {m2w1,            128, 2, 16};
  pa.jb[7] = {m2w1 + 64 * 128, 128, 2, 16};
  pa.jb[8] = {row1,            128, 2, 16};
  pa.jb[9] = {row2,            128, 4, 32};
  pa.Qw = Qw; pa.Qb = Qb;
  pa.g1wih = g1wih; pa.g1whh = g1whh;
  pa.g2wih = g2wih; pa.g2whh = g2whh;
  const int packTotal = TOTAL_CHUNKS * 512;
  k_pack<<<(packTotal + 255) / 256, 256, 0, stream>>>(pa, wb, packTotal);

  const int gN = (N + 63) / 64;
  const int gF = (F + 63) / 64;
  const int gE = (E + 63) / 64;

  for (int step = 0; step < NSTEPS; ++step) {
    // ---- var -> factor ----
    k_dense2<<<gN + gF, 256, 0, stream>>>(var_h, PB_w1as, Abuf, N, gN,
                                          fac_h, PB_w1ad, Bbuf, F, nullptr);
    k_edge<true><<<gE, 256, 0, stream>>>(Abuf, Bbuf, v2f_src, v2f_dst, feat_v2f,
                                         m1b1, m1b2, m1b3, PB_w2a, PB_w3a, PB_q, msgF, E);
    k_gru<<<gF, 256, 0, stream>>>(msgF, fac_h, PB_g1, g1bih, g1bhh, F);
    // ---- factor -> var ----
    k_dense2<<<gF + gN, 256, 0, stream>>>(fac_h, PB_w1bs, Abuf, F, gF,
                                          var_h, PB_w1bd, Bbuf, N, msgV);
    k_edge<false><<<gE, 256, 0, stream>>>(Abuf, Bbuf, f2v_src, f2v_dst, feat_f2v,
                                          m2b1, m2b2, m2b3, PB_w2b, PB_w3b, PB_q, msgV, E);
    k_gru<<<gN, 256, 0, stream>>>(msgV, var_h, PB_g2, g2bih, g2bhh, N);
  }

  // ---- readout ----
  k_dense<2><<<gN, 256, 0, stream>>>(var_h, PB_ro1, rob1, T1, N);
  k_dense<4><<<gN, 256, 0, stream>>>(T1,    PB_ro2, rob2, T2, N);
  k_readout<<<(N + 255) / 256, 256, 0, stream>>>(T2, row3, rob3, (float*)d_out, N);
}

// Round 4
// 717.071 us; speedup vs baseline: 3.9676x; 1.1507x over previous
//
#include <hip/hip_runtime.h>

#define NSTEPS 10

typedef __attribute__((ext_vector_type(8))) short bf16x8;
typedef __attribute__((ext_vector_type(4))) short bf16x4;
typedef __attribute__((ext_vector_type(4))) float f32x4;

__device__ __forceinline__ float sigmoidf_(float x) { return 1.0f / (1.0f + __expf(-x)); }
__device__ __forceinline__ float tanh_fast(float x) {
  const float e = __expf(2.f * x);
  return 1.f - 2.f / (e + 1.f);
}

// fp32 -> bf16 round-to-nearest-even (one-time weight pack)
__device__ __forceinline__ short bf16_(float x) {
  union { float f; unsigned u; } c; c.f = x;
  unsigned r = (c.u + 0x7FFFu + ((c.u >> 16) & 1u)) >> 16;
  return (short)r;
}
// fast activation packing (round-half-up): 1 add/elem + 1 perm/2 elems
__device__ __forceinline__ unsigned pk2_(float a, float b) {
  union { float f; unsigned u; } ca, cb; ca.f = a; cb.f = b;
  return __builtin_amdgcn_perm(cb.u + 0x8000u, ca.u + 0x8000u, 0x07060302u);
}
__device__ __forceinline__ short pk1_(float a) {
  union { float f; unsigned u; } c; c.f = a;
  return (short)((c.u + 0x8000u) >> 16);
}
__device__ __forceinline__ float lo_(unsigned u) { union { unsigned u; float f; } c; c.u = u << 16; return c.f; }
__device__ __forceinline__ float hi_(unsigned u) { union { unsigned u; float f; } c; c.u = u & 0xffff0000u; return c.f; }

__device__ __forceinline__ f32x4 mfma_16x16x32(bf16x8 a, bf16x8 b, f32x4 c) {
  return __builtin_amdgcn_mfma_f32_16x16x32_bf16(a, b, c, 0, 0, 0);
}

// ---------------------------------------------------------------------------
// k_pack: fp32 weights -> bf16 B-fragment chunks (one-time). See round-3 notes.
// ---------------------------------------------------------------------------
struct PackJob { const float* src; int N; int KS; int nchunks; };
struct PackArgs {
  PackJob jb[10];
  const float* Qw; const float* Qb;
  const float* g1wih; const float* g1whh;
  const float* g2wih; const float* g2whh;
};

__global__ __launch_bounds__(256) void k_pack(PackArgs a, short* __restrict__ out, int total) {
  const int g = blockIdx.x * 256 + threadIdx.x;
  if (g >= total) return;
  int c = g >> 9;
  const int r = g & 511;
  const int j = r & 7, n = (r >> 3) & 15, q = (r >> 7) & 3;
  const int kq = q * 8 + j;
  float val = 0.f;
  bool done = false;
  #pragma unroll
  for (int ji = 0; ji < 10; ++ji) {
    if (!done && c < a.jb[ji].nchunks) {
      const int ks = c % a.jb[ji].KS;
      const int nt = c / a.jb[ji].KS;
      const int k = ks * 32 + kq;
      val = a.jb[ji].src[(size_t)k * a.jb[ji].N + nt * 16 + n];
      done = true;
    }
    if (!done) c -= a.jb[ji].nchunks;
  }
  if (!done) {
    if (c < 5) {  // q-transform chunks (K padded 16->32)
      val = 0.f;
      if (kq < 16) val = (c < 4) ? a.Qw[c * 256 + n * 16 + kq] : a.Qb[n * 16 + kq];
    } else {      // GRU chunks: 256 cols = [r|z|in|hn], K=96 = [msg16|h64|pad16]
      c -= 5;
      const float* wih = (c < 48) ? a.g1wih : a.g2wih;
      const float* whh = (c < 48) ? a.g1whh : a.g2whh;
      if (c >= 48) c -= 48;
      const int nt = c / 3, ks = c % 3;
      const int k = ks * 32 + kq;
      const int ng = nt * 16 + n;
      const int gate = ng >> 6, s = ng & 63;
      val = 0.f;
      if (gate == 0) {
        if (k < 16) val = wih[k * 192 + s];
        else if (k < 80) val = whh[(k - 16) * 192 + s];
      } else if (gate == 1) {
        if (k < 16) val = wih[k * 192 + 64 + s];
        else if (k < 80) val = whh[(k - 16) * 192 + 64 + s];
      } else if (gate == 2) {
        if (k < 16) val = wih[k * 192 + 128 + s];
      } else {
        if (k >= 16 && k < 80) val = whh[(k - 16) * 192 + 128 + s];
      }
    }
  }
  out[g] = bf16_(val);
}

// ---------------------------------------------------------------------------
// k_dense2: two layer-1 partial GEMMs (K=64) in one dispatch, bf16 output.
// job0 (blocks [0,g0)): optional fused var-GRU prologue (gruMsg != nullptr):
//   h = GRU(msg, h) computed in-register, written to global h AND directly
//   into the LDS A-tile for the layer-1 partial.
// job1: plain; optional msg zeroing (zeroPtr).
// ---------------------------------------------------------------------------
__global__ __launch_bounds__(256) void k_dense2(
    const float* __restrict__ X0, const short* __restrict__ W0, short* __restrict__ C0,
    int rows0, int g0,
    const float* __restrict__ X1, const short* __restrict__ W1, short* __restrict__ C1,
    int rows1, float* __restrict__ zeroPtr,
    const float* __restrict__ gruMsg, float* __restrict__ gruH,
    const short* __restrict__ gruW,
    const float* __restrict__ gbih, const float* __restrict__ gbhh)
{
  constexpr int KS = 2, K = 64, STR = K + 8;
  __shared__ short Xs[64 * STR];
  __shared__ short SA[64 * 104];   // GRU A: [msg16|h64|pad16] + 8 pad
  const int t = threadIdx.x, lane = t & 63, wave = t >> 6;
  const int m = lane & 15, quad = lane >> 4;

  const float* X; const short* Wf; short* C; int rows, rbase;
  const bool job0 = (int)blockIdx.x < g0;
  if (job0) {
    X = X0; Wf = W0; C = C0; rows = rows0; rbase = blockIdx.x * 64;
  } else {
    X = X1; Wf = W1; C = C1; rows = rows1; rbase = ((int)blockIdx.x - g0) * 64;
    if (zeroPtr) {
      const int zr = rbase + (t >> 2);
      if (zr < rows1) {
        f32x4 z = {0.f, 0.f, 0.f, 0.f};
        *(f32x4*)(zeroPtr + (size_t)zr * 16 + (t & 3) * 4) = z;
      }
    }
  }

  bf16x8 b[2][KS];
  #pragma unroll
  for (int nt2 = 0; nt2 < 2; ++nt2)
    #pragma unroll
    for (int ks = 0; ks < KS; ++ks)
      b[nt2][ks] = ((const bf16x8*)Wf)[((wave * 2 + nt2) * KS + ks) * 64 + lane];

  if (job0 && gruMsg) {
    // ---- fused var-GRU prologue ----
    {
      const int r = t >> 2, q4 = t & 3, rg = rbase + r;
      #pragma unroll
      for (int i = 0; i < 6; ++i) {
        const int c = q4 * 4 + i * 16;   // 0..92 step 4
        f32x4 v = {0.f, 0.f, 0.f, 0.f};
        if (rg < rows) {
          if (c < 16)      v = *(const f32x4*)(gruMsg + (size_t)rg * 16 + c);
          else if (c < 80) v = *(const f32x4*)(gruH + (size_t)rg * 64 + (c - 16));
        }
        *(unsigned*)&SA[r * 104 + c]     = pk2_(v.x, v.y);
        *(unsigned*)&SA[r * 104 + c + 2] = pk2_(v.z, v.w);
      }
    }
    __syncthreads();
    f32x4 acc[16] = {};
    #pragma unroll
    for (int ks = 0; ks < 3; ++ks) {
      const bf16x8 a = *(const bf16x8*)&SA[(wave * 16 + m) * 104 + ks * 32 + quad * 8];
      #pragma unroll
      for (int nt = 0; nt < 16; ++nt)
        acc[nt] = mfma_16x16x32(a, ((const bf16x8*)gruW)[(nt * 3 + ks) * 64 + lane], acc[nt]);
    }
    #pragma unroll
    for (int nt = 0; nt < 4; ++nt) {
      const int s = nt * 16 + m;
      const float br  = gbih[s] + gbhh[s];
      const float bz  = gbih[64 + s] + gbhh[64 + s];
      const float bin = gbih[128 + s];
      const float bhn = gbhh[128 + s];
      #pragma unroll
      for (int reg = 0; reg < 4; ++reg) {
        const int lr = wave * 16 + quad * 4 + reg;
        const int rg = rbase + lr;
        short hv = 0;
        if (rg < rows) {
          const float ho = gruH[(size_t)rg * 64 + s];
          const float rr = sigmoidf_(acc[nt][reg] + br);
          const float zz = sigmoidf_(acc[4 + nt][reg] + bz);
          const float nn = tanh_fast(acc[8 + nt][reg] + bin + rr * (acc[12 + nt][reg] + bhn));
          const float hn = (1.f - zz) * nn + zz * ho;
          gruH[(size_t)rg * 64 + s] = hn;
          hv = pk1_(hn);
        }
        Xs[lr * STR + s] = hv;
      }
    }
    __syncthreads();
  } else {
    const int r = t >> 2, q4 = t & 3, rg = rbase + r;
    #pragma unroll
    for (int i = 0; i < K / 16; ++i) {
      const int cc = q4 * 4 + i * 16;
      f32x4 v = {0.f, 0.f, 0.f, 0.f};
      if (rg < rows) v = *(const f32x4*)(X + (size_t)rg * K + cc);
      *(unsigned*)&Xs[r * STR + cc]     = pk2_(v.x, v.y);
      *(unsigned*)&Xs[r * STR + cc + 2] = pk2_(v.z, v.w);
    }
    __syncthreads();
  }

  f32x4 acc[2][4] = {};
  #pragma unroll
  for (int ks = 0; ks < KS; ++ks) {
    bf16x8 afr[4];
    #pragma unroll
    for (int mt = 0; mt < 4; ++mt)
      afr[mt] = *(const bf16x8*)&Xs[(mt * 16 + m) * STR + ks * 32 + quad * 8];
    #pragma unroll
    for (int nt2 = 0; nt2 < 2; ++nt2)
      #pragma unroll
      for (int mt = 0; mt < 4; ++mt)
        acc[nt2][mt] = mfma_16x16x32(afr[mt], b[nt2][ks], acc[nt2][mt]);
  }

  #pragma unroll
  for (int nt2 = 0; nt2 < 2; ++nt2) {
    const int col = (wave * 2 + nt2) * 16 + m;
    #pragma unroll
    for (int mt = 0; mt < 4; ++mt)
      #pragma unroll
      for (int rr = 0; rr < 4; ++rr) {
        const int rg = rbase + mt * 16 + quad * 4 + rr;
        if (rg < rows) C[(size_t)rg * 128 + col] = pk1_(acc[nt2][mt][rr]);
      }
  }
}

// ---------------------------------------------------------------------------
// k_edge: fused edge MLP + q-transform; PAIRED additionally fuses the factor
// GRU for its 32 block-local factors (no msgF global round-trip at all).
// ---------------------------------------------------------------------------
template<bool PAIRED>
__global__ __launch_bounds__(256) void k_edge(
    const short* __restrict__ Pa, const short* __restrict__ Pb,
    const int* __restrict__ src, const int* __restrict__ dst,
    const float* __restrict__ feat,
    const float* __restrict__ b1, const float* __restrict__ b2,
    const float* __restrict__ b3,
    const short* __restrict__ w2f, const short* __restrict__ w3f,
    const short* __restrict__ qf,
    float* __restrict__ outMsg,
    float* __restrict__ facH, const short* __restrict__ gruW,
    const float* __restrict__ gbih, const float* __restrict__ gbhh,
    int E, int F)
{
  __shared__ short h1s[64 * 136];
  __shared__ short ms[64 * 40];
  __shared__ short AsG[32 * 104];  // PAIRED only: GRU A [msg16|h64|pad16]
  __shared__ float feats[64 * 4];
  __shared__ int sidx[64], didx[64];

  const int t = threadIdx.x, lane = t & 63, wave = t >> 6;
  const int e0 = blockIdx.x * 64;
  const int f0 = e0 >> 1;

  if (t < 64) {
    const int eg = e0 + t;
    sidx[t] = (eg < E) ? src[eg] : 0;
    didx[t] = (eg < E) ? dst[eg] : 0;
  }
  {
    const int e = t >> 2, k = t & 3;
    const int eg = e0 + e;
    feats[e * 4 + k] = (eg < E) ? feat[(size_t)eg * 4 + k] : 0.f;
  }
  if (PAIRED) {
    // stage pre-GRU h rows f0..f0+31 into AsG cols 16..79 (bf16), zero pad 80..95
    const int hr = t >> 3, hc = (t & 7) * 8;
    const int f = f0 + hr;
    f32x4 a0 = {0.f,0.f,0.f,0.f}, a1 = {0.f,0.f,0.f,0.f};
    if (f < F) {
      a0 = *(const f32x4*)(facH + (size_t)f * 64 + hc);
      a1 = *(const f32x4*)(facH + (size_t)f * 64 + hc + 4);
    }
    uint4 o;
    o.x = pk2_(a0.x, a0.y); o.y = pk2_(a0.z, a0.w);
    o.z = pk2_(a1.x, a1.y); o.w = pk2_(a1.z, a1.w);
    *(uint4*)&AsG[hr * 104 + 16 + hc] = o;
    if (t < 64) {
      uint4 z = make_uint4(0u, 0u, 0u, 0u);
      *(uint4*)&AsG[(t >> 1) * 104 + 80 + (t & 1) * 8] = z;
    }
  }
  bf16x8 bw2[2][4];
  #pragma unroll
  for (int nt2 = 0; nt2 < 2; ++nt2)
    #pragma unroll
    for (int ks = 0; ks < 4; ++ks)
      bw2[nt2][ks] = ((const bf16x8*)w2f)[((wave * 2 + nt2) * 4 + ks) * 64 + lane];
  __syncthreads();

  // stage h1 = relu(Pa[src]+Pb[dst]+b1)
  {
    const int r = t >> 2, q4 = t & 3;
    const bool ok = (e0 + r) < E;
    const short* pa = Pa + (size_t)sidx[r] * 128;
    const short* pb = Pb + (size_t)didx[r] * 128;
    #pragma unroll
    for (int i = 0; i < 4; ++i) {
      const int col = (q4 + i * 4) * 8;
      uint4 o = make_uint4(0u, 0u, 0u, 0u);
      if (ok) {
        const uint4 ua = *(const uint4*)(pa + col);
        const uint4 ub = *(const uint4*)(pb + col);
        const f32x4 ba = *(const f32x4*)(b1 + col);
        const f32x4 bb = *(const f32x4*)(b1 + col + 4);
        o.x = pk2_(fmaxf(lo_(ua.x) + lo_(ub.x) + ba.x, 0.f),
                   fmaxf(hi_(ua.x) + hi_(ub.x) + ba.y, 0.f));
        o.y = pk2_(fmaxf(lo_(ua.y) + lo_(ub.y) + ba.z, 0.f),
                   fmaxf(hi_(ua.y) + hi_(ub.y) + ba.w, 0.f));
        o.z = pk2_(fmaxf(lo_(ua.z) + lo_(ub.z) + bb.x, 0.f),
                   fmaxf(hi_(ua.z) + hi_(ub.z) + bb.y, 0.f));
        o.w = pk2_(fmaxf(lo_(ua.w) + lo_(ub.w) + bb.z, 0.f),
                   fmaxf(hi_(ua.w) + hi_(ub.w) + bb.w, 0.f));
      }
      *(uint4*)&h1s[r * 136 + col] = o;
    }
  }
  __syncthreads();

  const int m = lane & 15, quad = lane >> 4;

  // ---- layer 2 ----
  f32x4 acc2[2][4] = {};
  #pragma unroll
  for (int ks = 0; ks < 4; ++ks) {
    bf16x8 afr[4];
    #pragma unroll
    for (int mt = 0; mt < 4; ++mt)
      afr[mt] = *(const bf16x8*)&h1s[(mt * 16 + m) * 136 + ks * 32 + quad * 8];
    #pragma unroll
    for (int nt2 = 0; nt2 < 2; ++nt2)
      #pragma unroll
      for (int mt = 0; mt < 4; ++mt)
        acc2[nt2][mt] = mfma_16x16x32(afr[mt], bw2[nt2][ks], acc2[nt2][mt]);
  }
  __syncthreads();

  // h2 back to LDS (bias+relu)
  #pragma unroll
  for (int nt2 = 0; nt2 < 2; ++nt2) {
    const int col = (wave * 2 + nt2) * 16 + m;
    const float bv = b2[col];
    #pragma unroll
    for (int mt = 0; mt < 4; ++mt)
      #pragma unroll
      for (int rr = 0; rr < 4; ++rr)
        h1s[(mt * 16 + quad * 4 + rr) * 136 + col] =
            pk1_(fmaxf(acc2[nt2][mt][rr] + bv, 0.f));
  }
  bf16x8 bw3[4];
  #pragma unroll
  for (int ks = 0; ks < 4; ++ks) bw3[ks] = ((const bf16x8*)w3f)[ks * 64 + lane];
  bf16x8 bq[5];
  #pragma unroll
  for (int tq = 0; tq < 5; ++tq) bq[tq] = ((const bf16x8*)qf)[tq * 64 + lane];
  __syncthreads();

  // ---- layer 3 (wave = m-tile) ----
  f32x4 acc3 = {};
  #pragma unroll
  for (int ks = 0; ks < 4; ++ks) {
    const bf16x8 afr = *(const bf16x8*)&h1s[(wave * 16 + m) * 136 + ks * 32 + quad * 8];
    acc3 = mfma_16x16x32(afr, bw3[ks], acc3);
  }
  const float b3v = b3[m];
  #pragma unroll
  for (int rr = 0; rr < 4; ++rr) {
    const int row = wave * 16 + quad * 4 + rr;
    ms[row * 40 + m] = pk1_(acc3[rr] + b3v);
    ms[row * 40 + 16 + m] = 0;
  }
  __syncthreads();

  // ---- q transform ----
  f32x4 accY[5] = {};
  {
    const bf16x8 afr = *(const bf16x8*)&ms[(wave * 16 + m) * 40 + quad * 8];
    #pragma unroll
    for (int tq = 0; tq < 5; ++tq) accY[tq] = mfma_16x16x32(afr, bq[tq], accY[tq]);
  }
  float mq[4];
  #pragma unroll
  for (int rr = 0; rr < 4; ++rr) {
    const int row = wave * 16 + quad * 4 + rr;
    const f32x4 f = *(const f32x4*)&feats[row * 4];
    mq[rr] = accY[4][rr] + f.x * accY[0][rr] + f.y * accY[1][rr]
                         + f.z * accY[2][rr] + f.w * accY[3][rr];
  }

  if (PAIRED) {
    // pair-sum -> AsG msg cols; then fused factor GRU on 32 local rows
    {
      const int fl = wave * 8 + quad * 2;
      AsG[fl * 104 + m]       = pk1_(mq[0] + mq[1]);
      AsG[(fl + 1) * 104 + m] = pk1_(mq[2] + mq[3]);
    }
    __syncthreads();
    const int mt = wave >> 1, sh = wave & 1;
    f32x4 accG[8] = {};  // [gate*2 + nt2]
    #pragma unroll
    for (int ks = 0; ks < 3; ++ks) {
      const bf16x8 a = *(const bf16x8*)&AsG[(mt * 16 + m) * 104 + ks * 32 + quad * 8];
      #pragma unroll
      for (int g = 0; g < 4; ++g)
        #pragma unroll
        for (int nt2 = 0; nt2 < 2; ++nt2) {
          const int nt = g * 4 + sh * 2 + nt2;
          accG[g * 2 + nt2] =
              mfma_16x16x32(a, ((const bf16x8*)gruW)[(nt * 3 + ks) * 64 + lane],
                            accG[g * 2 + nt2]);
        }
    }
    #pragma unroll
    for (int nt2 = 0; nt2 < 2; ++nt2) {
      const int s = sh * 32 + nt2 * 16 + m;
      const float br  = gbih[s] + gbhh[s];
      const float bz  = gbih[64 + s] + gbhh[64 + s];
      const float bin = gbih[128 + s];
      const float bhn = gbhh[128 + s];
      #pragma unroll
      for (int reg = 0; reg < 4; ++reg) {
        const int f = f0 + mt * 16 + quad * 4 + reg;
        if (f < F) {
          const float ho = facH[(size_t)f * 64 + s];
          const float rr = sigmoidf_(accG[nt2][reg] + br);
          const float zz = sigmoidf_(accG[2 + nt2][reg] + bz);
          const float nn = tanh_fast(accG[4 + nt2][reg] + bin +
                                     rr * (accG[6 + nt2][reg] + bhn));
          facH[(size_t)f * 64 + s] = (1.f - zz) * nn + zz * ho;
        }
      }
    }
  } else {
    #pragma unroll
    for (int rr = 0; rr < 4; ++rr) {
      const int erow = wave * 16 + quad * 4 + rr;
      if (e0 + erow < E)
        atomicAdd(outMsg + (size_t)didx[erow] * 16 + m, mq[rr]);
    }
  }
}

// ---------------------------------------------------------------------------
// k_readout_f: fused final var-GRU + RO1 + RO2 + RO3 + softmax, all row-local.
// ---------------------------------------------------------------------------
__global__ __launch_bounds__(256) void k_readout_f(
    const float* __restrict__ gruMsg, const float* __restrict__ gruH,
    const short* __restrict__ gruW,
    const float* __restrict__ gbih, const float* __restrict__ gbhh,
    const short* __restrict__ ro1f, const float* __restrict__ rob1,
    const short* __restrict__ ro2f, const float* __restrict__ rob2,
    const float* __restrict__ row3, const float* __restrict__ rob3,
    float* __restrict__ out, int rows)
{
  __shared__ short SA[64 * 104];
  __shared__ short SH[64 * 72];
  __shared__ short S1[64 * 136];
  __shared__ short S2[64 * 136];
  __shared__ float w3s[256];
  const int t = threadIdx.x, lane = t & 63, wave = t >> 6;
  const int m = lane & 15, quad = lane >> 4;
  const int rbase = blockIdx.x * 64;

  w3s[t] = row3[t];

  // ---- GRU prologue ----
  {
    const int r = t >> 2, q4 = t & 3, rg = rbase + r;
    #pragma unroll
    for (int i = 0; i < 6; ++i) {
      const int c = q4 * 4 + i * 16;
      f32x4 v = {0.f, 0.f, 0.f, 0.f};
      if (rg < rows) {
        if (c < 16)      v = *(const f32x4*)(gruMsg + (size_t)rg * 16 + c);
        else if (c < 80) v = *(const f32x4*)(gruH + (size_t)rg * 64 + (c - 16));
      }
      *(unsigned*)&SA[r * 104 + c]     = pk2_(v.x, v.y);
      *(unsigned*)&SA[r * 104 + c + 2] = pk2_(v.z, v.w);
    }
  }
  __syncthreads();
  {
    f32x4 acc[16] = {};
    #pragma unroll
    for (int ks = 0; ks < 3; ++ks) {
      const bf16x8 a = *(const bf16x8*)&SA[(wave * 16 + m) * 104 + ks * 32 + quad * 8];
      #pragma unroll
      for (int nt = 0; nt < 16; ++nt)
        acc[nt] = mfma_16x16x32(a, ((const bf16x8*)gruW)[(nt * 3 + ks) * 64 + lane], acc[nt]);
    }
    #pragma unroll
    for (int nt = 0; nt < 4; ++nt) {
      const int s = nt * 16 + m;
      const float br  = gbih[s] + gbhh[s];
      const float bz  = gbih[64 + s] + gbhh[64 + s];
      const float bin = gbih[128 + s];
      const float bhn = gbhh[128 + s];
      #pragma unroll
      for (int reg = 0; reg < 4; ++reg) {
        const int lr = wave * 16 + quad * 4 + reg;
        const int rg = rbase + lr;
        short hv = 0;
        if (rg < rows) {
          const float ho = gruH[(size_t)rg * 64 + s];
          const float rr = sigmoidf_(acc[nt][reg] + br);
          const float zz = sigmoidf_(acc[4 + nt][reg] + bz);
          const float nn = tanh_fast(acc[8 + nt][reg] + bin + rr * (acc[12 + nt][reg] + bhn));
          hv = pk1_((1.f - zz) * nn + zz * ho);
        }
        SH[lr * 72 + s] = hv;
      }
    }
  }
  __syncthreads();

  // ---- RO1: SH[64x64] @ ro1 -> S1 ----
  {
    f32x4 acc[2][4] = {};
    #pragma unroll
    for (int ks = 0; ks < 2; ++ks) {
      bf16x8 afr[4];
      #pragma unroll
      for (int mt = 0; mt < 4; ++mt)
        afr[mt] = *(const bf16x8*)&SH[(mt * 16 + m) * 72 + ks * 32 + quad * 8];
      #pragma unroll
      for (int nt2 = 0; nt2 < 2; ++nt2) {
        const bf16x8 bb = ((const bf16x8*)ro1f)[((wave * 2 + nt2) * 2 + ks) * 64 + lane];
        #pragma unroll
        for (int mt = 0; mt < 4; ++mt)
          acc[nt2][mt] = mfma_16x16x32(afr[mt], bb, acc[nt2][mt]);
      }
    }
    #pragma unroll
    for (int nt2 = 0; nt2 < 2; ++nt2) {
      const int col = (wave * 2 + nt2) * 16 + m;
      const float bv = rob1[col];
      #pragma unroll
      for (int mt = 0; mt < 4; ++mt)
        #pragma unroll
        for (int rr = 0; rr < 4; ++rr)
          S1[(mt * 16 + quad * 4 + rr) * 136 + col] =
              pk1_(fmaxf(acc[nt2][mt][rr] + bv, 0.f));
    }
  }
  __syncthreads();

  // ---- RO2: S1[64x128] @ ro2 -> S2 ----
  {
    f32x4 acc[2][4] = {};
    #pragma unroll
    for (int ks = 0; ks < 4; ++ks) {
      bf16x8 afr[4];
      #pragma unroll
      for (int mt = 0; mt < 4; ++mt)
        afr[mt] = *(const bf16x8*)&S1[(mt * 16 + m) * 136 + ks * 32 + quad * 8];
      #pragma unroll
      for (int nt2 = 0; nt2 < 2; ++nt2) {
        const bf16x8 bb = ((const bf16x8*)ro2f)[((wave * 2 + nt2) * 4 + ks) * 64 + lane];
        #pragma unroll
        for (int mt = 0; mt < 4; ++mt)
          acc[nt2][mt] = mfma_16x16x32(afr[mt], bb, acc[nt2][mt]);
      }
    }
    #pragma unroll
    for (int nt2 = 0; nt2 < 2; ++nt2) {
      const int col = (wave * 2 + nt2) * 16 + m;
      const float bv = rob2[col];
      #pragma unroll
      for (int mt = 0; mt < 4; ++mt)
        #pragma unroll
        for (int rr = 0; rr < 4; ++rr)
          S2[(mt * 16 + quad * 4 + rr) * 136 + col] =
              pk1_(fmaxf(acc[nt2][mt][rr] + bv, 0.f));
    }
  }
  __syncthreads();

  // ---- RO3 + softmax (64 threads, one row each) ----
  if (t < 64) {
    const int rg = rbase + t;
    if (rg < rows) {
      float l0 = rob3[0], l1 = rob3[1];
      #pragma unroll 8
      for (int k = 0; k < 128; k += 2) {
        const unsigned u = *(const unsigned*)&S2[t * 136 + k];
        const float x0 = lo_(u), x1 = hi_(u);
        l0 = fmaf(x0, w3s[k * 2 + 0], l0);
        l1 = fmaf(x0, w3s[k * 2 + 1], l1);
        l0 = fmaf(x1, w3s[k * 2 + 2], l0);
        l1 = fmaf(x1, w3s[k * 2 + 3], l1);
      }
      const float mx = fmaxf(l0, l1);
      const float e0 = __expf(l0 - mx), e1 = __expf(l1 - mx);
      const float inv = 1.f / (e0 + e1);
      out[(size_t)rg * 2 + 0] = e0 * inv;
      out[(size_t)rg * 2 + 1] = e1 * inv;
    }
  }
}

// ---------------------------------------------------------------------------
extern "C" void kernel_launch(void* const* d_in, const int* in_sizes, int n_in,
                              void* d_out, int out_size, void* d_ws, size_t ws_size,
                              hipStream_t stream)
{
  const int*   v2f_src  = (const int*)d_in[0];
  const int*   v2f_dst  = (const int*)d_in[1];
  const int*   f2v_src  = (const int*)d_in[2];
  const int*   f2v_dst  = (const int*)d_in[3];
  const float* feat_v2f = (const float*)d_in[4];
  const float* feat_f2v = (const float*)d_in[5];
  const float* Qw    = (const float*)d_in[8];
  const float* Qb    = (const float*)d_in[9];
  const float* m1w1  = (const float*)d_in[10];
  const float* m1b1  = (const float*)d_in[11];
  const float* m1w2  = (const float*)d_in[12];
  const float* m1b2  = (const float*)d_in[13];
  const float* m1w3  = (const float*)d_in[14];
  const float* m1b3  = (const float*)d_in[15];
  const float* m2w1  = (const float*)d_in[16];
  const float* m2b1  = (const float*)d_in[17];
  const float* m2w2  = (const float*)d_in[18];
  const float* m2b2  = (const float*)d_in[19];
  const float* m2w3  = (const float*)d_in[20];
  const float* m2b3  = (const float*)d_in[21];
  const float* g1wih = (const float*)d_in[22];
  const float* g1whh = (const float*)d_in[23];
  const float* g1bih = (const float*)d_in[24];
  const float* g1bhh = (const float*)d_in[25];
  const float* g2wih = (const float*)d_in[26];
  const float* g2whh = (const float*)d_in[27];
  const float* g2bih = (const float*)d_in[28];
  const float* g2bhh = (const float*)d_in[29];
  const float* row1  = (const float*)d_in[30];
  const float* rob1  = (const float*)d_in[31];
  const float* row2  = (const float*)d_in[32];
  const float* rob2  = (const float*)d_in[33];
  const float* row3  = (const float*)d_in[34];
  const float* rob3  = (const float*)d_in[35];

  const int E = in_sizes[0];
  const int N = out_size / 2;
  const int F = E / 2;

  // ---- workspace layout ----
  float* ws    = (float*)d_ws;
  float* var_h = ws;                               // N*64 f32
  float* fac_h = var_h + (size_t)N * 64;           // F*64 f32
  float* msgV  = fac_h + (size_t)F * 64;           // N*16 f32
  short* Abuf  = (short*)(msgV + (size_t)N * 16);  // F*128 bf16
  short* Bbuf  = Abuf + (size_t)F * 128;           // F*128 bf16
  short* wb    = Bbuf + (size_t)F * 128;           // packed weights

  // chunk offsets (1 chunk = 512 bf16)
  const int C_W2A = 0,  C_W2B = 32, C_W3A = 64, C_W3B = 68;
  const int C_W1AS = 72, C_W1AD = 88, C_W1BS = 104, C_W1BD = 120;
  const int C_RO1 = 136, C_RO2 = 152, C_Q = 184, C_G1 = 189, C_G2 = 237;
  const int TOTAL_CHUNKS = 285;

  short* PB_w2a  = wb + C_W2A  * 512;
  short* PB_w2b  = wb + C_W2B  * 512;
  short* PB_w3a  = wb + C_W3A  * 512;
  short* PB_w3b  = wb + C_W3B  * 512;
  short* PB_w1as = wb + C_W1AS * 512;
  short* PB_w1ad = wb + C_W1AD * 512;
  short* PB_w1bs = wb + C_W1BS * 512;
  short* PB_w1bd = wb + C_W1BD * 512;
  short* PB_ro1  = wb + C_RO1  * 512;
  short* PB_ro2  = wb + C_RO2  * 512;
  short* PB_q    = wb + C_Q    * 512;
  short* PB_g1   = wb + C_G1   * 512;
  short* PB_g2   = wb + C_G2   * 512;

  hipMemsetAsync(var_h, 0, (size_t)N * 64 * sizeof(float), stream);
  hipMemsetAsync(fac_h, 0, (size_t)F * 64 * sizeof(float), stream);

  PackArgs pa;
  pa.jb[0] = {m1w2,            128, 4, 32};
  pa.jb[1] = {m2w2,            128, 4, 32};
  pa.jb[2] = {m1w3,             16, 4,  4};
  pa.jb[3] = {m2w3,             16, 4,  4};
  pa.jb[4] = {m1w1,            128, 2, 16};
  pa.jb[5] = {m1w1 + 64 * 128, 128, 2, 16};
  pa.jb[6] = {m2w1,            128, 2, 16};
  pa.jb[7] = {m2w1 + 64 * 128, 128, 2, 16};
  pa.jb[8] = {row1,            128, 2, 16};
  pa.jb[9] = {row2,            128, 4, 32};
  pa.Qw = Qw; pa.Qb = Qb;
  pa.g1wih = g1wih; pa.g1whh = g1whh;
  pa.g2wih = g2wih; pa.g2whh = g2whh;
  const int packTotal = TOTAL_CHUNKS * 512;
  k_pack<<<(packTotal + 255) / 256, 256, 0, stream>>>(pa, wb, packTotal);

  const int gN = (N + 63) / 64;
  const int gF = (F + 63) / 64;
  const int gE = (E + 63) / 64;

  for (int step = 0; step < NSTEPS; ++step) {
    // ---- phase 1: layer-1 partials for v2f (+ fused var-GRU for steps > 0) ----
    k_dense2<<<gN + gF, 256, 0, stream>>>(
        var_h, PB_w1as, Abuf, N, gN,
        fac_h, PB_w1ad, Bbuf, F, nullptr,
        step ? msgV : nullptr, var_h, PB_g2, g2bih, g2bhh);
    // ---- phase 2: v2f edges + fused factor-GRU ----
    k_edge<true><<<gE, 256, 0, stream>>>(
        Abuf, Bbuf, v2f_src, v2f_dst, feat_v2f, m1b1, m1b2, m1b3,
        PB_w2a, PB_w3a, PB_q, nullptr, fac_h, PB_g1, g1bih, g1bhh, E, F);
    // ---- phase 3: layer-1 partials for f2v (+ zero msgV) ----
    k_dense2<<<gF + gN, 256, 0, stream>>>(
        fac_h, PB_w1bs, Abuf, F, gF,
        var_h, PB_w1bd, Bbuf, N, msgV,
        nullptr, nullptr, nullptr, nullptr, nullptr);
    // ---- phase 4: f2v edges -> msgV atomics (var-GRU deferred) ----
    k_edge<false><<<gE, 256, 0, stream>>>(
        Abuf, Bbuf, f2v_src, f2v_dst, feat_f2v, m2b1, m2b2, m2b3,
        PB_w2b, PB_w3b, PB_q, msgV, nullptr, nullptr, nullptr, nullptr, E, F);
  }

  // ---- fused readout: final var-GRU + MLP + softmax ----
  k_readout_f<<<gN, 256, 0, stream>>>(
      msgV, var_h, PB_g2, g2bih, g2bhh,
      PB_ro1, rob1, PB_ro2, rob2, row3, rob3, (float*)d_out, N);
}